// Round 2
// baseline (1652.098 us; speedup 1.0000x reference)
//
#include <hip/hip_runtime.h>
#include <hip/hip_bf16.h>
#include <cstdint>
#include <cstddef>

typedef unsigned short u16;
typedef unsigned int   u32;

typedef short s16x8 __attribute__((ext_vector_type(8)));
typedef float f32x4 __attribute__((ext_vector_type(4)));

__device__ __forceinline__ float b2f(u16 u){ u32 x = ((u32)u)<<16; float f; __builtin_memcpy(&f,&x,4); return f; }
__device__ __forceinline__ u16  f2b(float f){ u32 x; __builtin_memcpy(&x,&f,4); u32 r = x + 0x7FFFu + ((x>>16)&1u); return (u16)(r>>16); }

__device__ __forceinline__ void unpack8(uint4 v, float* o){
  o[0]=b2f((u16)v.x); o[1]=b2f((u16)(v.x>>16));
  o[2]=b2f((u16)v.y); o[3]=b2f((u16)(v.y>>16));
  o[4]=b2f((u16)v.z); o[5]=b2f((u16)(v.z>>16));
  o[6]=b2f((u16)v.w); o[7]=b2f((u16)(v.w>>16));
}

__device__ __forceinline__ void gl_lds16(const u16* g, u16* l){
  __builtin_amdgcn_global_load_lds((const __attribute__((address_space(1))) u32*)g,
                                   (__attribute__((address_space(3))) u32*)l, 16, 0, 0);
}

// ---------------- dtype detect: ln_w[0]==1.0; bf16 -> first u16 = 0x3F80, fp32 -> 0x0000 ----------------
__global__ void k_detect(const u16* __restrict__ lnw, int* __restrict__ flag){
  if (threadIdx.x==0 && blockIdx.x==0) *flag = (lnw[0] == 0x3F80) ? 1 : 0;
}

// ---------------- convert all weight tensors to canonical bf16 ----------------
struct CvtTable { const void* src[14]; u16* dst[14]; int n[14]; };
__global__ void k_cvt(CvtTable t, const int* __restrict__ flag){
  int ti = blockIdx.y;
  int n = t.n[ti];
  int isbf = *flag;
  const u16*  sb = (const u16*)t.src[ti];
  const float* sf = (const float*)t.src[ti];
  u16* d = t.dst[ti];
  for (int i = blockIdx.x*256 + threadIdx.x; i < n; i += gridDim.x*256)
    d[i] = isbf ? sb[i] : f2b(sf[i]);
}

// ---------------- segment mean: data (32,256,4096) -> x (8,4096,256) fp32 ----------------
__global__ void k_mean(const void* __restrict__ data, const int* __restrict__ rl,
                       float* __restrict__ x, const int* __restrict__ flag){
  __shared__ float tile[32][129];
  int isbf = *flag;
  const u16*  db = (const u16*)data;
  const float* df_ = (const float*)data;
  int g = blockIdx.z, c0 = blockIdx.y*32, l0 = blockIdx.x*128;
  int tid = threadIdx.x;
  int off=0; for(int i=0;i<g;i++) off += rl[i];
  int cnt = rl[g];
  float inv = 1.0f/(float)cnt;
  for(int it=0; it<16; ++it){
    int idx = it*256 + tid;
    int ci = idx>>7, lj = idx&127;
    float acc = 0.f;
    for(int b=0;b<cnt;b++){
      size_t gi = ((size_t)(off+b)*256 + (c0+ci)) * 4096 + (l0+lj);
      acc += isbf ? b2f(db[gi]) : df_[gi];
    }
    tile[ci][lj] = acc*inv;
  }
  __syncthreads();
  for(int it=0; it<16; ++it){
    int idx = it*256 + tid;
    int lj = idx>>5, ci = idx&31;
    x[ ((size_t)g*4096 + (l0+lj))*256 + (c0+ci) ] = tile[ci][lj];
  }
}

// ---------------- Bcomb prep: rows 0..255 = dt_proj_w @ x_proj_w[:16]; 256..271 = x_proj_w[16:32]; 272..383 = 0 ----------------
__global__ void k_prep(const u16* __restrict__ dtp, const u16* __restrict__ xpw, u16* __restrict__ bcomb){
  int layer = blockIdx.y, row = blockIdx.x, c = threadIdx.x;
  u16 out;
  if (row < 256){
    float acc = 0.f;
    #pragma unroll
    for(int r=0;r<16;r++)
      acc += b2f(dtp[(size_t)layer*4096 + row*16 + r]) * b2f(xpw[(size_t)layer*8192 + r*256 + c]);
    out = f2b(acc);
  } else if (row < 272){
    out = xpw[(size_t)layer*8192 + (16 + row - 256)*256 + c];
  } else {
    out = 0;
  }
  bcomb[((size_t)layer*384 + row)*256 + c] = out;
}

// ---------------- LN1: x fp32 -> xn bf16 (one wave per row of 256) ----------------
__global__ void k_ln1(const float* __restrict__ x, u16* __restrict__ xn,
                      const u16* __restrict__ w, const u16* __restrict__ b, int layer){
  int wid = threadIdx.x>>6, lane = threadIdx.x&63;
  int row = blockIdx.x*4 + wid;
  const float* xr = x + (size_t)row*256;
  float4 v = *(const float4*)(xr + lane*4);
  float s = v.x+v.y+v.z+v.w;
  float q = v.x*v.x+v.y*v.y+v.z*v.z+v.w*v.w;
  for(int o=32;o;o>>=1){ s += __shfl_xor(s,o); q += __shfl_xor(q,o); }
  float mu = s*(1.f/256.f);
  float var = q*(1.f/256.f) - mu*mu;
  float rs = rsqrtf(var + 1e-5f);
  const u16* wp = w + layer*256 + lane*4;
  const u16* bp = b + layer*256 + lane*4;
  float vv[4] = {v.x,v.y,v.z,v.w};
  u16 o4[4];
  #pragma unroll
  for(int k2=0;k2<4;k2++) o4[k2] = f2b( (vv[k2]-mu)*rs*b2f(wp[k2]) + b2f(bp[k2]) );
  uint2 ov; ov.x = (u32)o4[0] | ((u32)o4[1]<<16); ov.y = (u32)o4[2] | ((u32)o4[3]<<16);
  *(uint2*)(xn + (size_t)row*256 + lane*4) = ov;
}

// ---------------- bf16 NT GEMM, 128x128 tile, K=256, ldA=ldB=256 ----------------
template<int MODE>
__global__ __launch_bounds__(256)
void k_gemm(const u16* __restrict__ A, const u16* __restrict__ B,
            u16* __restrict__ C0, int ldC,
            const u16* __restrict__ bias, u16* __restrict__ C1){
  __shared__ u16 As[128*32];
  __shared__ u16 Bs[128*32];
  int tid = threadIdx.x, wid = tid>>6, lane = tid&63;
  int m0 = blockIdx.x*128, n0 = blockIdx.y*128;
  f32x4 acc[4][4];
  #pragma unroll
  for(int i=0;i<4;i++)
    #pragma unroll
    for(int j=0;j<4;j++) acc[i][j] = (f32x4){0.f,0.f,0.f,0.f};
  int srow = wid*32 + (lane>>2);
  int scol = (lane&3)*8;
  int rm = (wid&1)*64, cn = (wid>>1)*64;
  for(int k0=0;k0<256;k0+=32){
    #pragma unroll
    for(int i=0;i<2;i++){
      int ro = srow + i*16;
      gl_lds16(A + (size_t)(m0+ro)*256 + k0 + scol, As + (wid*2+i)*512 + lane*8);
      gl_lds16(B + (size_t)(n0+ro)*256 + k0 + scol, Bs + (wid*2+i)*512 + lane*8);
    }
    __syncthreads();
    s16x8 af[4], bfr[4];
    #pragma unroll
    for(int i=0;i<4;i++){
      af[i]  = *(const s16x8*)(As + (rm + i*16 + (lane&15))*32 + (lane>>4)*8);
      bfr[i] = *(const s16x8*)(Bs + (cn + i*16 + (lane&15))*32 + (lane>>4)*8);
    }
    #pragma unroll
    for(int i=0;i<4;i++)
      #pragma unroll
      for(int j=0;j<4;j++)
        acc[i][j] = __builtin_amdgcn_mfma_f32_16x16x32_bf16(af[i], bfr[j], acc[i][j], 0,0,0);
    __syncthreads();
  }
  #pragma unroll
  for(int i=0;i<4;i++){
    #pragma unroll
    for(int j=0;j<4;j++){
      int n  = n0 + cn + j*16 + (lane&15);
      int mB = m0 + rm + i*16 + ((lane>>4)<<2);
      #pragma unroll
      for(int r=0;r<4;r++){
        float val = acc[i][j][r];
        int m = mB + r;
        if (MODE==0){
          C0[(size_t)m*ldC + n] = f2b(val);
        } else {
          if (n < 256){
            float v2 = val + b2f(bias[n]);
            float sp = (v2 > 15.f) ? v2 : log1pf(__expf(v2));
            C0[(size_t)m*256 + n] = f2b(sp);
          } else if (n < 272){
            C1[(size_t)m*16 + (n-256)] = f2b(val);
          }
        }
      }
    }
  }
}

// ---------------- depthwise causal conv (fwd) + anti-causal (bwd) + SiLU ----------------
__global__ void k_conv(const u16* __restrict__ xz, const u16* __restrict__ cw,
                       const u16* __restrict__ cb, u16* __restrict__ xcf, u16* __restrict__ xcb_, int layer){
  int l = blockIdx.x, g = blockIdx.y, d = threadIdx.x;
  float w[4];
  #pragma unroll
  for(int j=0;j<4;j++) w[j] = b2f(cw[(size_t)layer*1024 + d*4 + j]);
  float bb = b2f(cb[layer*256 + d]);
  float xv[7];
  #pragma unroll
  for(int t=0;t<7;t++){
    int lp = l - 3 + t;
    xv[t] = (lp>=0 && lp<4096) ? b2f(xz[((size_t)g*4096 + lp)*512 + d]) : 0.f;
  }
  float af = bb, ab = bb;
  #pragma unroll
  for(int j=0;j<4;j++){ af += w[j]*xv[j]; ab += w[j]*xv[6-j]; }
  af = af / (1.f + __expf(-af));
  ab = ab / (1.f + __expf(-ab));
  size_t o = ((size_t)g*4096 + l)*256 + d;
  xcf[o]  = f2b(af);
  xcb_[o] = f2b(ab);
}

// ---------------- scan pass 1: per-chunk transitions ----------------
__global__ __launch_bounds__(256)
void k_scan1(const u16* __restrict__ df, const u16* __restrict__ db,
             const u16* __restrict__ uf, const u16* __restrict__ ub,
             const u16* __restrict__ bcf, const u16* __restrict__ bcb,
             const u16* __restrict__ Alog, const u16* __restrict__ Ablog,
             float* __restrict__ abuf, float* __restrict__ bbuf, int layer){
  int c = blockIdx.x, g = blockIdx.y, dir = blockIdx.z, d = threadIdx.x;
  const u16* dl = dir ? db : df;
  const u16* uu = dir ? ub : uf;
  const u16* bc = dir ? bcb : bcf;
  const u16* Al = dir ? Ablog : Alog;
  float An[8], h[8], ap[8];
  #pragma unroll
  for(int n=0;n<8;n++){
    An[n] = -__expf(b2f(Al[(size_t)layer*2048 + d*8 + n]));
    h[n] = 0.f; ap[n] = 1.f;
  }
  #pragma unroll 4
  for(int t=0;t<64;t++){
    int ts = c*64 + t;
    int tg = dir ? (4095 - ts) : ts;
    size_t rowo = (size_t)g*4096 + tg;
    float dv = b2f(dl[rowo*256 + d]);
    float uv = b2f(uu[rowo*256 + d]);
    uint4 bv = *(const uint4*)(bc + rowo*16);
    float bn[8]; unpack8(bv, bn);
    float du = dv*uv;
    #pragma unroll
    for(int n=0;n<8;n++){
      float da = __expf(dv*An[n]);
      h[n] = fmaf(da, h[n], du*bn[n]);
      ap[n] *= da;
    }
  }
  size_t base = ((((size_t)dir*8+g)*64 + c)*256 + d)*8;
  *(float4*)(abuf+base)   = (float4){ap[0],ap[1],ap[2],ap[3]};
  *(float4*)(abuf+base+4) = (float4){ap[4],ap[5],ap[6],ap[7]};
  *(float4*)(bbuf+base)   = (float4){h[0],h[1],h[2],h[3]};
  *(float4*)(bbuf+base+4) = (float4){h[4],h[5],h[6],h[7]};
}

// ---------------- scan pass 2: sequential combine across 64 chunks ----------------
__global__ void k_scan2(const float* __restrict__ abuf, const float* __restrict__ bbuf,
                        float* __restrict__ hs){
  int dblk = blockIdx.x, g = blockIdx.y, dir = blockIdx.z;
  int n = threadIdx.x & 7, dd = threadIdx.x >> 3;
  int d = dblk*32 + dd;
  float h = 0.f;
  size_t gofs = (((size_t)dir*8+g)*64);
  for(int c=0;c<64;c++){
    size_t idx = ((gofs + c)*256 + d)*8 + n;
    hs[idx] = h;
    h = fmaf(abuf[idx], h, bbuf[idx]);
  }
}

// ---------------- scan pass 3: replay with correct h0, emit gated y ----------------
__global__ __launch_bounds__(256)
void k_scan3(const u16* __restrict__ df, const u16* __restrict__ db,
             const u16* __restrict__ uf, const u16* __restrict__ ub,
             const u16* __restrict__ bcf, const u16* __restrict__ bcb,
             const u16* __restrict__ Alog, const u16* __restrict__ Ablog,
             const u16* __restrict__ Dp, const u16* __restrict__ xz,
             const float* __restrict__ hs,
             u16* __restrict__ yf, u16* __restrict__ yb, int layer){
  int c = blockIdx.x, g = blockIdx.y, dir = blockIdx.z, d = threadIdx.x;
  const u16* dl = dir ? db : df;
  const u16* uu = dir ? ub : uf;
  const u16* bc = dir ? bcb : bcf;
  const u16* Al = dir ? Ablog : Alog;
  u16* yo = dir ? yb : yf;
  float An[8], h[8];
  size_t base = ((((size_t)dir*8+g)*64 + c)*256 + d)*8;
  float4 h0 = *(const float4*)(hs+base);
  float4 h1 = *(const float4*)(hs+base+4);
  h[0]=h0.x; h[1]=h0.y; h[2]=h0.z; h[3]=h0.w;
  h[4]=h1.x; h[5]=h1.y; h[6]=h1.z; h[7]=h1.w;
  #pragma unroll
  for(int n=0;n<8;n++) An[n] = -__expf(b2f(Al[(size_t)layer*2048 + d*8 + n]));
  float Dd = b2f(Dp[layer*256 + d]);
  #pragma unroll 2
  for(int t=0;t<64;t++){
    int ts = c*64 + t;
    int tg = dir ? (4095 - ts) : ts;
    size_t rowo = (size_t)g*4096 + tg;
    float dv = b2f(dl[rowo*256 + d]);
    float uv = b2f(uu[rowo*256 + d]);
    uint4 bv = *(const uint4*)(bc + rowo*16);
    uint4 cv = *(const uint4*)(bc + rowo*16 + 8);
    float bn[8], cn_[8];
    unpack8(bv, bn); unpack8(cv, cn_);
    float du = dv*uv;
    float y = 0.f;
    #pragma unroll
    for(int n=0;n<8;n++){
      float da = __expf(dv*An[n]);
      h[n] = fmaf(da, h[n], du*bn[n]);
      y = fmaf(h[n], cn_[n], y);
    }
    y += Dd*uv;
    float zv = b2f(xz[rowo*512 + 256 + d]);
    y *= zv / (1.f + __expf(-zv));
    yo[rowo*256 + d] = f2b(y);
  }
}

// ---------------- combine: yc = 0.5*(yf+yb), bf16 ----------------
__global__ void k_comb(const u16* __restrict__ yf, const u16* __restrict__ yb, u16* __restrict__ yc){
  size_t i = ((size_t)blockIdx.x*256 + threadIdx.x)*8;
  uint4 a = *(const uint4*)(yf+i);
  uint4 b = *(const uint4*)(yb+i);
  float fa[8], fb[8]; unpack8(a,fa); unpack8(b,fb);
  u32 o[4];
  #pragma unroll
  for(int k2=0;k2<4;k2++){
    u16 lo = f2b(0.5f*(fa[2*k2]  +fb[2*k2]));
    u16 hi = f2b(0.5f*(fa[2*k2+1]+fb[2*k2+1]));
    o[k2] = (u32)lo | ((u32)hi<<16);
  }
  *(uint4*)(yc+i) = (uint4){o[0],o[1],o[2],o[3]};
}

// ---------------- LN2 + residual ----------------
__global__ void k_ln2(const u16* __restrict__ ob, float* __restrict__ x,
                      const u16* __restrict__ w, const u16* __restrict__ b, int layer){
  int wid = threadIdx.x>>6, lane = threadIdx.x&63;
  int row = blockIdx.x*4 + wid;
  uint2 iv = *(const uint2*)(ob + (size_t)row*256 + lane*4);
  float v[4] = { b2f((u16)iv.x), b2f((u16)(iv.x>>16)), b2f((u16)iv.y), b2f((u16)(iv.y>>16)) };
  float s = v[0]+v[1]+v[2]+v[3];
  float q = v[0]*v[0]+v[1]*v[1]+v[2]*v[2]+v[3]*v[3];
  for(int o=32;o;o>>=1){ s += __shfl_xor(s,o); q += __shfl_xor(q,o); }
  float mu = s*(1.f/256.f);
  float var = q*(1.f/256.f) - mu*mu;
  float rs = rsqrtf(var+1e-5f);
  float4* xp = (float4*)(x + (size_t)row*256 + lane*4);
  float4 xv = *xp;
  float xa[4] = {xv.x,xv.y,xv.z,xv.w};
  const u16* wp = w + layer*256 + lane*4;
  const u16* bp = b + layer*256 + lane*4;
  float oo[4];
  #pragma unroll
  for(int k2=0;k2<4;k2++) oo[k2] = xa[k2] + (v[k2]-mu)*rs*b2f(wp[k2]) + b2f(bp[k2]);
  *xp = (float4){oo[0],oo[1],oo[2],oo[3]};
}

// ---------------- final transpose: x (8,4096,256) fp32 -> out (8,256,4096) bf16 or fp32 ----------------
__global__ void k_tr(const float* __restrict__ x, void* __restrict__ out, const int* __restrict__ flag){
  __shared__ float tile[32][129];
  int isbf = *flag;
  int l0 = blockIdx.x*128, c0 = blockIdx.y*32, g = blockIdx.z;
  int tid = threadIdx.x;
  for(int it=0; it<16; ++it){
    int idx = it*256 + tid;
    int lj = idx>>5, ci = idx&31;
    tile[ci][lj] = x[((size_t)g*4096 + l0+lj)*256 + c0+ci];
  }
  __syncthreads();
  for(int it=0; it<16; ++it){
    int idx = it*256 + tid;
    int lj = idx&127, ci = idx>>7;
    size_t o = ((size_t)g*256 + c0+ci)*4096 + l0+lj;
    float v = tile[ci][lj];
    if (isbf) ((u16*)out)[o] = f2b(v);
    else      ((float*)out)[o] = v;
  }
}

extern "C" void kernel_launch(void* const* d_in, const int* in_sizes, int n_in,
                              void* d_out, int out_size, void* d_ws, size_t ws_size,
                              hipStream_t stream){
  (void)in_sizes; (void)n_in; (void)out_size; (void)ws_size;
  const int* rl = (const int*)d_in[15];

  char* ws = (char*)d_ws;
  float* X    = (float*)(ws);                    // 32 MB fp32 residual
  u16*  XN    = (u16*)(ws + 33554432);           // 16 MB; reused as ycomb
  u16*  XZ    = (u16*)(ws + 50331648);           // 32 MB (g,l,512)
  u16*  XCF   = (u16*)(ws + 83886080);           // 16 MB
  u16*  XCB   = (u16*)(ws + 100663296);          // 16 MB
  u16*  DF    = (u16*)(ws + 117440512);          // 16 MB; reused as outb
  u16*  DB    = (u16*)(ws + 134217728);          // 16 MB
  u16*  BCF   = (u16*)(ws + 150994944);          // 1 MB
  u16*  BCB   = (u16*)(ws + 152043520);          // 1 MB
  u16*  BCOMB = (u16*)(ws + 153092096);          // 0.75 MB
  float* ABUF = (float*)(ws + 153878528);        // 8 MB
  float* BBUF = (float*)(ws + 162267136);        // 8 MB
  u16*  YF    = (u16*)(ws + 153878528);          // 16 MB (reuses ABUF+BBUF after pass2)
  float* HS   = (float*)(ws + 170655744);        // 8 MB
  u16*  YB    = (u16*)(ws + 179044352);          // 16 MB
  u16*  WCVT  = (u16*)(ws + 195821568);          // ~1.7 MB canonical bf16 weights
  int*  FLAG  = (int*)(ws + 197918720);
  u16*  YC    = XN;
  u16*  OUTB  = DF;

  // canonical bf16 weight pointers (element offsets within WCVT)
  u16* W_lnw  = WCVT + 0;
  u16* W_lnb  = WCVT + 1024;
  u16* W_inp  = WCVT + 2048;
  u16* W_cw   = WCVT + 526336;
  u16* W_cb   = WCVT + 530432;
  u16* W_xp   = WCVT + 531456;
  u16* W_dtw  = WCVT + 564224;
  u16* W_dtb  = WCVT + 580608;
  u16* W_Al   = WCVT + 581632;
  u16* W_Abl  = WCVT + 589824;
  u16* W_D    = WCVT + 598016;
  u16* W_outp = WCVT + 599040;
  u16* W_mnw  = WCVT + 861184;
  u16* W_mnb  = WCVT + 862208;

  k_detect<<<1,64,0,stream>>>((const u16*)d_in[1], FLAG);

  CvtTable t;
  const int idxs[14] = {1,2,3,4,5,6,7,8,9,10,11,12,13,14};
  u16* dsts[14] = {W_lnw,W_lnb,W_inp,W_cw,W_cb,W_xp,W_dtw,W_dtb,W_Al,W_Abl,W_D,W_outp,W_mnw,W_mnb};
  const int ns[14] = {1024,1024,524288,4096,1024,32768,16384,1024,8192,8192,1024,262144,1024,1024};
  for(int i=0;i<14;i++){ t.src[i]=d_in[idxs[i]]; t.dst[i]=dsts[i]; t.n[i]=ns[i]; }
  k_cvt<<<dim3(32,14),256,0,stream>>>(t, FLAG);

  k_mean<<<dim3(32,8,8),256,0,stream>>>(d_in[0], rl, X, FLAG);
  k_prep<<<dim3(384,4),256,0,stream>>>(W_dtw, W_xp, BCOMB);

  for(int layer=0; layer<4; ++layer){
    k_ln1<<<8192,256,0,stream>>>(X, XN, W_lnw, W_lnb, layer);
    k_gemm<0><<<dim3(256,4),256,0,stream>>>(XN, W_inp + (size_t)layer*512*256, XZ, 512, nullptr, nullptr);
    k_conv<<<dim3(4096,8),256,0,stream>>>(XZ, W_cw, W_cb, XCF, XCB, layer);
    k_gemm<1><<<dim3(256,3),256,0,stream>>>(XCF, BCOMB + (size_t)layer*384*256, DF, 256, W_dtb + layer*256, BCF);
    k_gemm<1><<<dim3(256,3),256,0,stream>>>(XCB, BCOMB + (size_t)layer*384*256, DB, 256, W_dtb + layer*256, BCB);
    k_scan1<<<dim3(64,8,2),256,0,stream>>>(DF,DB,XCF,XCB,BCF,BCB,W_Al,W_Abl,ABUF,BBUF,layer);
    k_scan2<<<dim3(8,8,2),256,0,stream>>>(ABUF,BBUF,HS);
    k_scan3<<<dim3(64,8,2),256,0,stream>>>(DF,DB,XCF,XCB,BCF,BCB,W_Al,W_Abl,W_D,XZ,HS,YF,YB,layer);
    k_comb<<<4096,256,0,stream>>>(YF,YB,YC);
    k_gemm<0><<<dim3(256,2),256,0,stream>>>(YC, W_outp + (size_t)layer*256*256, OUTB, 256, nullptr, nullptr);
    k_ln2<<<8192,256,0,stream>>>(OUTB, X, W_mnw, W_mnb, layer);
  }
  k_tr<<<dim3(32,8,8),256,0,stream>>>(X, d_out, FLAG);
}

// Round 3
// 1260.648 us; speedup vs baseline: 1.3105x; 1.3105x over previous
//
#include <hip/hip_runtime.h>
#include <hip/hip_bf16.h>
#include <cstdint>
#include <cstddef>

typedef unsigned short u16;
typedef unsigned int   u32;

typedef short s16x8 __attribute__((ext_vector_type(8)));
typedef float f32x4 __attribute__((ext_vector_type(4)));

__device__ __forceinline__ float b2f(u16 u){ u32 x = ((u32)u)<<16; float f; __builtin_memcpy(&f,&x,4); return f; }
__device__ __forceinline__ u16  f2b(float f){ u32 x; __builtin_memcpy(&x,&f,4); u32 r = x + 0x7FFFu + ((x>>16)&1u); return (u16)(r>>16); }

__device__ __forceinline__ void unpack8(uint4 v, float* o){
  o[0]=b2f((u16)v.x); o[1]=b2f((u16)(v.x>>16));
  o[2]=b2f((u16)v.y); o[3]=b2f((u16)(v.y>>16));
  o[4]=b2f((u16)v.z); o[5]=b2f((u16)(v.z>>16));
  o[6]=b2f((u16)v.w); o[7]=b2f((u16)(v.w>>16));
}

__device__ __forceinline__ void gl_lds16(const u16* g, u16* l){
  __builtin_amdgcn_global_load_lds((const __attribute__((address_space(1))) u32*)g,
                                   (__attribute__((address_space(3))) u32*)l, 16, 0, 0);
}

// ---------------- dtype detect ----------------
__global__ void k_detect(const u16* __restrict__ lnw, int* __restrict__ flag){
  if (threadIdx.x==0 && blockIdx.x==0) *flag = (lnw[0] == 0x3F80) ? 1 : 0;
}

// ---------------- convert weights to canonical bf16 ----------------
struct CvtTable { const void* src[14]; u16* dst[14]; int n[14]; };
__global__ void k_cvt(CvtTable t, const int* __restrict__ flag){
  int ti = blockIdx.y;
  int n = t.n[ti];
  int isbf = *flag;
  const u16*  sb = (const u16*)t.src[ti];
  const float* sf = (const float*)t.src[ti];
  u16* d = t.dst[ti];
  for (int i = blockIdx.x*256 + threadIdx.x; i < n; i += gridDim.x*256)
    d[i] = isbf ? sb[i] : f2b(sf[i]);
}

// ---------------- segment mean ----------------
__global__ void k_mean(const void* __restrict__ data, const int* __restrict__ rl,
                       float* __restrict__ x, const int* __restrict__ flag){
  __shared__ float tile[32][129];
  int isbf = *flag;
  const u16*  db = (const u16*)data;
  const float* df_ = (const float*)data;
  int g = blockIdx.z, c0 = blockIdx.y*32, l0 = blockIdx.x*128;
  int tid = threadIdx.x;
  int off=0; for(int i=0;i<g;i++) off += rl[i];
  int cnt = rl[g];
  float inv = 1.0f/(float)cnt;
  for(int it=0; it<16; ++it){
    int idx = it*256 + tid;
    int ci = idx>>7, lj = idx&127;
    float acc = 0.f;
    for(int b=0;b<cnt;b++){
      size_t gi = ((size_t)(off+b)*256 + (c0+ci)) * 4096 + (l0+lj);
      acc += isbf ? b2f(db[gi]) : df_[gi];
    }
    tile[ci][lj] = acc*inv;
  }
  __syncthreads();
  for(int it=0; it<16; ++it){
    int idx = it*256 + tid;
    int lj = idx>>5, ci = idx&31;
    x[ ((size_t)g*4096 + (l0+lj))*256 + (c0+ci) ] = tile[ci][lj];
  }
}

// ---------------- Bcomb prep ----------------
__global__ void k_prep(const u16* __restrict__ dtp, const u16* __restrict__ xpw, u16* __restrict__ bcomb){
  int layer = blockIdx.y, row = blockIdx.x, c = threadIdx.x;
  u16 out;
  if (row < 256){
    float acc = 0.f;
    #pragma unroll
    for(int r=0;r<16;r++)
      acc += b2f(dtp[(size_t)layer*4096 + row*16 + r]) * b2f(xpw[(size_t)layer*8192 + r*256 + c]);
    out = f2b(acc);
  } else if (row < 272){
    out = xpw[(size_t)layer*8192 + (16 + row - 256)*256 + c];
  } else {
    out = 0;
  }
  bcomb[((size_t)layer*384 + row)*256 + c] = out;
}

// ---------------- LN1 ----------------
__global__ void k_ln1(const float* __restrict__ x, u16* __restrict__ xn,
                      const u16* __restrict__ w, const u16* __restrict__ b, int layer){
  int wid = threadIdx.x>>6, lane = threadIdx.x&63;
  int row = blockIdx.x*4 + wid;
  const float* xr = x + (size_t)row*256;
  float4 v = *(const float4*)(xr + lane*4);
  float s = v.x+v.y+v.z+v.w;
  float q = v.x*v.x+v.y*v.y+v.z*v.z+v.w*v.w;
  for(int o=32;o;o>>=1){ s += __shfl_xor(s,o); q += __shfl_xor(q,o); }
  float mu = s*(1.f/256.f);
  float var = q*(1.f/256.f) - mu*mu;
  float rs = rsqrtf(var + 1e-5f);
  const u16* wp = w + layer*256 + lane*4;
  const u16* bp = b + layer*256 + lane*4;
  float vv[4] = {v.x,v.y,v.z,v.w};
  u16 o4[4];
  #pragma unroll
  for(int k2=0;k2<4;k2++) o4[k2] = f2b( (vv[k2]-mu)*rs*b2f(wp[k2]) + b2f(bp[k2]) );
  uint2 ov; ov.x = (u32)o4[0] | ((u32)o4[1]<<16); ov.y = (u32)o4[2] | ((u32)o4[3]<<16);
  *(uint2*)(xn + (size_t)row*256 + lane*4) = ov;
}

// ---------------- bf16 NT GEMM, 128x128 tile, BK=64, K=256, XOR-swizzled LDS ----------------
// MODE 0: plain store to C0 (ldC). MODE 1: n<256 -> softplus(acc+bias[n]) -> C0 (ld 256); 256<=n<272 -> C1 (ld 16).
template<int MODE>
__global__ __launch_bounds__(256)
void k_gemm(const u16* __restrict__ A, const u16* __restrict__ B,
            u16* __restrict__ C0, int ldC,
            const u16* __restrict__ bias, u16* __restrict__ C1){
  __shared__ u16 As[128*64];
  __shared__ u16 Bs[128*64];
  int tid = threadIdx.x, wid = tid>>6, lane = tid&63;
  int m0 = blockIdx.x*128, n0 = blockIdx.y*128;
  f32x4 acc[4][4];
  #pragma unroll
  for(int i=0;i<4;i++)
    #pragma unroll
    for(int j=0;j<4;j++) acc[i][j] = (f32x4){0.f,0.f,0.f,0.f};
  int lrow  = lane>>3;                 // row within 8-row chunk
  int scol  = ((lane&7) ^ lrow) * 8;   // swizzled source k-offset (u16)
  int rm = (wid&1)*64, cn = (wid>>1)*64;
  for(int k0=0;k0<256;k0+=64){
    #pragma unroll
    for(int it=0; it<4; ++it){
      int chunk = wid*4 + it;          // 0..15, rows chunk*8..+7
      int row = chunk*8 + lrow;
      gl_lds16(A + (size_t)(m0+row)*256 + k0 + scol, As + chunk*512 + lane*8);
      gl_lds16(B + (size_t)(n0+row)*256 + k0 + scol, Bs + chunk*512 + lane*8);
    }
    __syncthreads();
    #pragma unroll
    for(int kk=0;kk<2;kk++){
      s16x8 af[4], bfr[4];
      #pragma unroll
      for(int i=0;i<4;i++){
        int ar = rm + i*16 + (lane&15);
        int ap = (kk*4 + (lane>>4)) ^ (ar&7);
        af[i]  = *(const s16x8*)(As + ar*64 + ap*8);
        int br = cn + i*16 + (lane&15);
        int bp = (kk*4 + (lane>>4)) ^ (br&7);
        bfr[i] = *(const s16x8*)(Bs + br*64 + bp*8);
      }
      #pragma unroll
      for(int i=0;i<4;i++)
        #pragma unroll
        for(int j=0;j<4;j++)
          acc[i][j] = __builtin_amdgcn_mfma_f32_16x16x32_bf16(af[i], bfr[j], acc[i][j], 0,0,0);
    }
    __syncthreads();
  }
  #pragma unroll
  for(int i=0;i<4;i++){
    #pragma unroll
    for(int j=0;j<4;j++){
      int n  = n0 + cn + j*16 + (lane&15);
      int mB = m0 + rm + i*16 + ((lane>>4)<<2);
      #pragma unroll
      for(int r=0;r<4;r++){
        float val = acc[i][j][r];
        int m = mB + r;
        if (MODE==0){
          C0[(size_t)m*ldC + n] = f2b(val);
        } else {
          if (n < 256){
            float v2 = val + b2f(bias[n]);
            float sp = (v2 > 15.f) ? v2 : __logf(1.f + __expf(v2));
            C0[(size_t)m*256 + n] = f2b(sp);
          } else if (n < 272){
            C1[(size_t)m*16 + (n-256)] = f2b(val);
          }
        }
      }
    }
  }
}

// ---------------- depthwise conv + SiLU ----------------
__global__ void k_conv(const u16* __restrict__ xz, const u16* __restrict__ cw,
                       const u16* __restrict__ cb, u16* __restrict__ xcf, u16* __restrict__ xcb_, int layer){
  int l = blockIdx.x, g = blockIdx.y, d = threadIdx.x;
  float w[4];
  #pragma unroll
  for(int j=0;j<4;j++) w[j] = b2f(cw[(size_t)layer*1024 + d*4 + j]);
  float bb = b2f(cb[layer*256 + d]);
  float xv[7];
  #pragma unroll
  for(int t=0;t<7;t++){
    int lp = l - 3 + t;
    xv[t] = (lp>=0 && lp<4096) ? b2f(xz[((size_t)g*4096 + lp)*512 + d]) : 0.f;
  }
  float af = bb, ab = bb;
  #pragma unroll
  for(int j=0;j<4;j++){ af += w[j]*xv[j]; ab += w[j]*xv[6-j]; }
  af = af / (1.f + __expf(-af));
  ab = ab / (1.f + __expf(-ab));
  size_t o = ((size_t)g*4096 + l)*256 + d;
  xcf[o]  = f2b(af);
  xcb_[o] = f2b(ab);
}

// ---------------- scan pass 1 ----------------
__global__ __launch_bounds__(256)
void k_scan1(const u16* __restrict__ df, const u16* __restrict__ db,
             const u16* __restrict__ uf, const u16* __restrict__ ub,
             const u16* __restrict__ bcf, const u16* __restrict__ bcb,
             const u16* __restrict__ Alog, const u16* __restrict__ Ablog,
             float* __restrict__ abuf, float* __restrict__ bbuf, int layer){
  int c = blockIdx.x, g = blockIdx.y, dir = blockIdx.z, d = threadIdx.x;
  const u16* dl = dir ? db : df;
  const u16* uu = dir ? ub : uf;
  const u16* bc = dir ? bcb : bcf;
  const u16* Al = dir ? Ablog : Alog;
  float An[8], h[8], ap[8];
  #pragma unroll
  for(int n=0;n<8;n++){
    An[n] = -__expf(b2f(Al[(size_t)layer*2048 + d*8 + n]));
    h[n] = 0.f; ap[n] = 1.f;
  }
  #pragma unroll 4
  for(int t=0;t<64;t++){
    int ts = c*64 + t;
    int tg = dir ? (4095 - ts) : ts;
    size_t rowo = (size_t)g*4096 + tg;
    float dv = b2f(dl[rowo*256 + d]);
    float uv = b2f(uu[rowo*256 + d]);
    uint4 bv = *(const uint4*)(bc + rowo*16);
    float bn[8]; unpack8(bv, bn);
    float du = dv*uv;
    #pragma unroll
    for(int n=0;n<8;n++){
      float da = __expf(dv*An[n]);
      h[n] = fmaf(da, h[n], du*bn[n]);
      ap[n] *= da;
    }
  }
  size_t base = ((((size_t)dir*8+g)*64 + c)*256 + d)*8;
  *(float4*)(abuf+base)   = (float4){ap[0],ap[1],ap[2],ap[3]};
  *(float4*)(abuf+base+4) = (float4){ap[4],ap[5],ap[6],ap[7]};
  *(float4*)(bbuf+base)   = (float4){h[0],h[1],h[2],h[3]};
  *(float4*)(bbuf+base+4) = (float4){h[4],h[5],h[6],h[7]};
}

// ---------------- scan pass 2 ----------------
__global__ void k_scan2(const float* __restrict__ abuf, const float* __restrict__ bbuf,
                        float* __restrict__ hs){
  int dblk = blockIdx.x, g = blockIdx.y, dir = blockIdx.z;
  int n = threadIdx.x & 7, dd = threadIdx.x >> 3;
  int d = dblk*32 + dd;
  float h = 0.f;
  size_t gofs = (((size_t)dir*8+g)*64);
  for(int c=0;c<64;c++){
    size_t idx = ((gofs + c)*256 + d)*8 + n;
    hs[idx] = h;
    h = fmaf(abuf[idx], h, bbuf[idx]);
  }
}

// ---------------- scan pass 3 ----------------
__global__ __launch_bounds__(256)
void k_scan3(const u16* __restrict__ df, const u16* __restrict__ db,
             const u16* __restrict__ uf, const u16* __restrict__ ub,
             const u16* __restrict__ bcf, const u16* __restrict__ bcb,
             const u16* __restrict__ Alog, const u16* __restrict__ Ablog,
             const u16* __restrict__ Dp, const u16* __restrict__ xz,
             const float* __restrict__ hs,
             u16* __restrict__ yf, u16* __restrict__ yb, int layer){
  int c = blockIdx.x, g = blockIdx.y, dir = blockIdx.z, d = threadIdx.x;
  const u16* dl = dir ? db : df;
  const u16* uu = dir ? ub : uf;
  const u16* bc = dir ? bcb : bcf;
  const u16* Al = dir ? Ablog : Alog;
  u16* yo = dir ? yb : yf;
  float An[8], h[8];
  size_t base = ((((size_t)dir*8+g)*64 + c)*256 + d)*8;
  float4 h0 = *(const float4*)(hs+base);
  float4 h1 = *(const float4*)(hs+base+4);
  h[0]=h0.x; h[1]=h0.y; h[2]=h0.z; h[3]=h0.w;
  h[4]=h1.x; h[5]=h1.y; h[6]=h1.z; h[7]=h1.w;
  #pragma unroll
  for(int n=0;n<8;n++) An[n] = -__expf(b2f(Al[(size_t)layer*2048 + d*8 + n]));
  float Dd = b2f(Dp[layer*256 + d]);
  #pragma unroll 2
  for(int t=0;t<64;t++){
    int ts = c*64 + t;
    int tg = dir ? (4095 - ts) : ts;
    size_t rowo = (size_t)g*4096 + tg;
    float dv = b2f(dl[rowo*256 + d]);
    float uv = b2f(uu[rowo*256 + d]);
    uint4 bv = *(const uint4*)(bc + rowo*16);
    uint4 cv = *(const uint4*)(bc + rowo*16 + 8);
    float bn[8], cn_[8];
    unpack8(bv, bn); unpack8(cv, cn_);
    float du = dv*uv;
    float y = 0.f;
    #pragma unroll
    for(int n=0;n<8;n++){
      float da = __expf(dv*An[n]);
      h[n] = fmaf(da, h[n], du*bn[n]);
      y = fmaf(h[n], cn_[n], y);
    }
    y += Dd*uv;
    float zv = b2f(xz[rowo*512 + 256 + d]);
    y *= zv / (1.f + __expf(-zv));
    yo[rowo*256 + d] = f2b(y);
  }
}

// ---------------- combine ----------------
__global__ void k_comb(const u16* __restrict__ yf, const u16* __restrict__ yb, u16* __restrict__ yc){
  size_t i = ((size_t)blockIdx.x*256 + threadIdx.x)*8;
  uint4 a = *(const uint4*)(yf+i);
  uint4 b = *(const uint4*)(yb+i);
  float fa[8], fb[8]; unpack8(a,fa); unpack8(b,fb);
  u32 o[4];
  #pragma unroll
  for(int k2=0;k2<4;k2++){
    u16 lo = f2b(0.5f*(fa[2*k2]  +fb[2*k2]));
    u16 hi = f2b(0.5f*(fa[2*k2+1]+fb[2*k2+1]));
    o[k2] = (u32)lo | ((u32)hi<<16);
  }
  *(uint4*)(yc+i) = (uint4){o[0],o[1],o[2],o[3]};
}

// ---------------- LN2 + residual ----------------
__global__ void k_ln2(const u16* __restrict__ ob, float* __restrict__ x,
                      const u16* __restrict__ w, const u16* __restrict__ b, int layer){
  int wid = threadIdx.x>>6, lane = threadIdx.x&63;
  int row = blockIdx.x*4 + wid;
  uint2 iv = *(const uint2*)(ob + (size_t)row*256 + lane*4);
  float v[4] = { b2f((u16)iv.x), b2f((u16)(iv.x>>16)), b2f((u16)iv.y), b2f((u16)(iv.y>>16)) };
  float s = v[0]+v[1]+v[2]+v[3];
  float q = v[0]*v[0]+v[1]*v[1]+v[2]*v[2]+v[3]*v[3];
  for(int o=32;o;o>>=1){ s += __shfl_xor(s,o); q += __shfl_xor(q,o); }
  float mu = s*(1.f/256.f);
  float var = q*(1.f/256.f) - mu*mu;
  float rs = rsqrtf(var+1e-5f);
  float4* xp = (float4*)(x + (size_t)row*256 + lane*4);
  float4 xv = *xp;
  float xa[4] = {xv.x,xv.y,xv.z,xv.w};
  const u16* wp = w + layer*256 + lane*4;
  const u16* bp = b + layer*256 + lane*4;
  float oo[4];
  #pragma unroll
  for(int k2=0;k2<4;k2++) oo[k2] = xa[k2] + (v[k2]-mu)*rs*b2f(wp[k2]) + b2f(bp[k2]);
  *xp = (float4){oo[0],oo[1],oo[2],oo[3]};
}

// ---------------- final transpose ----------------
__global__ void k_tr(const float* __restrict__ x, void* __restrict__ out, const int* __restrict__ flag){
  __shared__ float tile[32][129];
  int isbf = *flag;
  int l0 = blockIdx.x*128, c0 = blockIdx.y*32, g = blockIdx.z;
  int tid = threadIdx.x;
  for(int it=0; it<16; ++it){
    int idx = it*256 + tid;
    int lj = idx>>5, ci = idx&31;
    tile[ci][lj] = x[((size_t)g*4096 + l0+lj)*256 + c0+ci];
  }
  __syncthreads();
  for(int it=0; it<16; ++it){
    int idx = it*256 + tid;
    int lj = idx&127, ci = idx>>7;
    size_t o = ((size_t)g*256 + c0+ci)*4096 + l0+lj;
    float v = tile[ci][lj];
    if (isbf) ((u16*)out)[o] = f2b(v);
    else      ((float*)out)[o] = v;
  }
}

extern "C" void kernel_launch(void* const* d_in, const int* in_sizes, int n_in,
                              void* d_out, int out_size, void* d_ws, size_t ws_size,
                              hipStream_t stream){
  (void)in_sizes; (void)n_in; (void)out_size; (void)ws_size;
  const int* rl = (const int*)d_in[15];

  char* ws = (char*)d_ws;
  float* X    = (float*)(ws);                    // 32 MB fp32 residual
  u16*  XN    = (u16*)(ws + 33554432);           // 16 MB; reused as ycomb
  u16*  XZ    = (u16*)(ws + 50331648);           // 32 MB (g,l,512)
  u16*  XCF   = (u16*)(ws + 83886080);           // 16 MB  (XCB contiguous after)
  u16*  XCB   = (u16*)(ws + 100663296);          // 16 MB
  u16*  DF    = (u16*)(ws + 117440512);          // 16 MB  (DB contiguous after); reused as outb
  u16*  DB    = (u16*)(ws + 134217728);          // 16 MB
  u16*  BCF   = (u16*)(ws + 150994944);          // 1 MB   (BCB contiguous after)
  u16*  BCB   = (u16*)(ws + 152043520);          // 1 MB
  u16*  BCOMB = (u16*)(ws + 153092096);          // 0.75 MB
  float* ABUF = (float*)(ws + 153878528);        // 8 MB
  float* BBUF = (float*)(ws + 162267136);        // 8 MB
  u16*  YF    = (u16*)(ws + 153878528);          // 16 MB (reuses ABUF+BBUF after pass2)
  float* HS   = (float*)(ws + 170655744);        // 8 MB
  u16*  YB    = (u16*)(ws + 179044352);          // 16 MB
  u16*  WCVT  = (u16*)(ws + 195821568);          // ~1.7 MB canonical bf16 weights
  int*  FLAG  = (int*)(ws + 197918720);
  u16*  YC    = XN;
  u16*  OUTB  = DF;

  u16* W_lnw  = WCVT + 0;
  u16* W_lnb  = WCVT + 1024;
  u16* W_inp  = WCVT + 2048;
  u16* W_cw   = WCVT + 526336;
  u16* W_cb   = WCVT + 530432;
  u16* W_xp   = WCVT + 531456;
  u16* W_dtw  = WCVT + 564224;
  u16* W_dtb  = WCVT + 580608;
  u16* W_Al   = WCVT + 581632;
  u16* W_Abl  = WCVT + 589824;
  u16* W_D    = WCVT + 598016;
  u16* W_outp = WCVT + 599040;
  u16* W_mnw  = WCVT + 861184;
  u16* W_mnb  = WCVT + 862208;

  k_detect<<<1,64,0,stream>>>((const u16*)d_in[1], FLAG);

  CvtTable t;
  const int idxs[14] = {1,2,3,4,5,6,7,8,9,10,11,12,13,14};
  u16* dsts[14] = {W_lnw,W_lnb,W_inp,W_cw,W_cb,W_xp,W_dtw,W_dtb,W_Al,W_Abl,W_D,W_outp,W_mnw,W_mnb};
  const int ns[14] = {1024,1024,524288,4096,1024,32768,16384,1024,8192,8192,1024,262144,1024,1024};
  for(int i=0;i<14;i++){ t.src[i]=d_in[idxs[i]]; t.dst[i]=dsts[i]; t.n[i]=ns[i]; }
  k_cvt<<<dim3(32,14),256,0,stream>>>(t, FLAG);

  k_mean<<<dim3(32,8,8),256,0,stream>>>(d_in[0], rl, X, FLAG);
  k_prep<<<dim3(384,4),256,0,stream>>>(W_dtw, W_xp, BCOMB);

  for(int layer=0; layer<4; ++layer){
    k_ln1<<<8192,256,0,stream>>>(X, XN, W_lnw, W_lnb, layer);
    k_gemm<0><<<dim3(256,4),256,0,stream>>>(XN, W_inp + (size_t)layer*512*256, XZ, 512, nullptr, nullptr);
    k_conv<<<dim3(4096,8),256,0,stream>>>(XZ, W_cw, W_cb, XCF, XCB, layer);
    // merged fwd+bwd delta/BC projection: A = [XCF;XCB] (M=65536), outputs [DF;DB], [BCF;BCB]
    k_gemm<1><<<dim3(512,3),256,0,stream>>>(XCF, BCOMB + (size_t)layer*384*256, DF, 256, W_dtb + layer*256, BCF);
    k_scan1<<<dim3(64,8,2),256,0,stream>>>(DF,DB,XCF,XCB,BCF,BCB,W_Al,W_Abl,ABUF,BBUF,layer);
    k_scan2<<<dim3(8,8,2),256,0,stream>>>(ABUF,BBUF,HS);
    k_scan3<<<dim3(64,8,2),256,0,stream>>>(DF,DB,XCF,XCB,BCF,BCB,W_Al,W_Abl,W_D,XZ,HS,YF,YB,layer);
    k_comb<<<4096,256,0,stream>>>(YF,YB,YC);
    k_gemm<0><<<dim3(256,2),256,0,stream>>>(YC, W_outp + (size_t)layer*256*256, OUTB, 256, nullptr, nullptr);
    k_ln2<<<8192,256,0,stream>>>(OUTB, X, W_mnw, W_mnb, layer);
  }
  k_tr<<<dim3(32,8,8),256,0,stream>>>(X, d_out, FLAG);
}

// Round 4
// 1147.371 us; speedup vs baseline: 1.4399x; 1.0987x over previous
//
#include <hip/hip_runtime.h>
#include <hip/hip_bf16.h>
#include <cstdint>
#include <cstddef>

typedef unsigned short u16;
typedef unsigned int   u32;

typedef short s16x8 __attribute__((ext_vector_type(8)));
typedef float f32x4 __attribute__((ext_vector_type(4)));

__device__ __forceinline__ float b2f(u16 u){ u32 x = ((u32)u)<<16; float f; __builtin_memcpy(&f,&x,4); return f; }
__device__ __forceinline__ u16  f2b(float f){ u32 x; __builtin_memcpy(&x,&f,4); u32 r = x + 0x7FFFu + ((x>>16)&1u); return (u16)(r>>16); }

__device__ __forceinline__ void unpack8(uint4 v, float* o){
  o[0]=b2f((u16)v.x); o[1]=b2f((u16)(v.x>>16));
  o[2]=b2f((u16)v.y); o[3]=b2f((u16)(v.y>>16));
  o[4]=b2f((u16)v.z); o[5]=b2f((u16)(v.z>>16));
  o[6]=b2f((u16)v.w); o[7]=b2f((u16)(v.w>>16));
}

__device__ __forceinline__ void gl_lds16(const u16* g, u16* l){
  __builtin_amdgcn_global_load_lds((const __attribute__((address_space(1))) u32*)g,
                                   (__attribute__((address_space(3))) u32*)l, 16, 0, 0);
}

// ---------------- dtype detect ----------------
__global__ void k_detect(const u16* __restrict__ lnw, int* __restrict__ flag){
  if (threadIdx.x==0 && blockIdx.x==0) *flag = (lnw[0] == 0x3F80) ? 1 : 0;
}

// ---------------- convert weights to canonical bf16 ----------------
struct CvtTable { const void* src[14]; u16* dst[14]; int n[14]; };
__global__ void k_cvt(CvtTable t, const int* __restrict__ flag){
  int ti = blockIdx.y;
  int n = t.n[ti];
  int isbf = *flag;
  const u16*  sb = (const u16*)t.src[ti];
  const float* sf = (const float*)t.src[ti];
  u16* d = t.dst[ti];
  for (int i = blockIdx.x*256 + threadIdx.x; i < n; i += gridDim.x*256)
    d[i] = isbf ? sb[i] : f2b(sf[i]);
}

// ---------------- segment mean ----------------
__global__ void k_mean(const void* __restrict__ data, const int* __restrict__ rl,
                       float* __restrict__ x, const int* __restrict__ flag){
  __shared__ float tile[32][129];
  int isbf = *flag;
  const u16*  db = (const u16*)data;
  const float* df_ = (const float*)data;
  int g = blockIdx.z, c0 = blockIdx.y*32, l0 = blockIdx.x*128;
  int tid = threadIdx.x;
  int off=0; for(int i=0;i<g;i++) off += rl[i];
  int cnt = rl[g];
  float inv = 1.0f/(float)cnt;
  for(int it=0; it<16; ++it){
    int idx = it*256 + tid;
    int ci = idx>>7, lj = idx&127;
    float acc = 0.f;
    for(int b=0;b<cnt;b++){
      size_t gi = ((size_t)(off+b)*256 + (c0+ci)) * 4096 + (l0+lj);
      acc += isbf ? b2f(db[gi]) : df_[gi];
    }
    tile[ci][lj] = acc*inv;
  }
  __syncthreads();
  for(int it=0; it<16; ++it){
    int idx = it*256 + tid;
    int lj = idx>>5, ci = idx&31;
    x[ ((size_t)g*4096 + (l0+lj))*256 + (c0+ci) ] = tile[ci][lj];
  }
}

// ---------------- Bcomb prep ----------------
__global__ void k_prep(const u16* __restrict__ dtp, const u16* __restrict__ xpw, u16* __restrict__ bcomb){
  int layer = blockIdx.y, row = blockIdx.x, c = threadIdx.x;
  u16 out;
  if (row < 256){
    float acc = 0.f;
    #pragma unroll
    for(int r=0;r<16;r++)
      acc += b2f(dtp[(size_t)layer*4096 + row*16 + r]) * b2f(xpw[(size_t)layer*8192 + r*256 + c]);
    out = f2b(acc);
  } else if (row < 272){
    out = xpw[(size_t)layer*8192 + (16 + row - 256)*256 + c];
  } else {
    out = 0;
  }
  bcomb[((size_t)layer*384 + row)*256 + c] = out;
}

// ---------------- LN1 (layer 0 only) ----------------
__global__ void k_ln1(const float* __restrict__ x, u16* __restrict__ xn,
                      const u16* __restrict__ w, const u16* __restrict__ b, int layer){
  int wid = threadIdx.x>>6, lane = threadIdx.x&63;
  int row = blockIdx.x*4 + wid;
  const float* xr = x + (size_t)row*256;
  float4 v = *(const float4*)(xr + lane*4);
  float s = v.x+v.y+v.z+v.w;
  float q = v.x*v.x+v.y*v.y+v.z*v.z+v.w*v.w;
  for(int o=32;o;o>>=1){ s += __shfl_xor(s,o); q += __shfl_xor(q,o); }
  float mu = s*(1.f/256.f);
  float var = q*(1.f/256.f) - mu*mu;
  float rs = rsqrtf(var + 1e-5f);
  const u16* wp = w + layer*256 + lane*4;
  const u16* bp = b + layer*256 + lane*4;
  float vv[4] = {v.x,v.y,v.z,v.w};
  u16 o4[4];
  #pragma unroll
  for(int k2=0;k2<4;k2++) o4[k2] = f2b( (vv[k2]-mu)*rs*b2f(wp[k2]) + b2f(bp[k2]) );
  uint2 ov; ov.x = (u32)o4[0] | ((u32)o4[1]<<16); ov.y = (u32)o4[2] | ((u32)o4[3]<<16);
  *(uint2*)(xn + (size_t)row*256 + lane*4) = ov;
}

// ---------------- bf16 NT GEMM, 128x128 tile, BK=64, K=256, XOR-swizzled LDS ----------------
template<int MODE>
__global__ __launch_bounds__(256)
void k_gemm(const u16* __restrict__ A, const u16* __restrict__ B,
            u16* __restrict__ C0, int ldC,
            const u16* __restrict__ bias, u16* __restrict__ C1){
  __shared__ u16 As[128*64];
  __shared__ u16 Bs[128*64];
  int tid = threadIdx.x, wid = tid>>6, lane = tid&63;
  int m0 = blockIdx.x*128, n0 = blockIdx.y*128;
  f32x4 acc[4][4];
  #pragma unroll
  for(int i=0;i<4;i++)
    #pragma unroll
    for(int j=0;j<4;j++) acc[i][j] = (f32x4){0.f,0.f,0.f,0.f};
  int lrow  = lane>>3;
  int scol  = ((lane&7) ^ lrow) * 8;
  int rm = (wid&1)*64, cn = (wid>>1)*64;
  for(int k0=0;k0<256;k0+=64){
    #pragma unroll
    for(int it=0; it<4; ++it){
      int chunk = wid*4 + it;
      int row = chunk*8 + lrow;
      gl_lds16(A + (size_t)(m0+row)*256 + k0 + scol, As + chunk*512 + lane*8);
      gl_lds16(B + (size_t)(n0+row)*256 + k0 + scol, Bs + chunk*512 + lane*8);
    }
    __syncthreads();
    #pragma unroll
    for(int kk=0;kk<2;kk++){
      s16x8 af[4], bfr[4];
      #pragma unroll
      for(int i=0;i<4;i++){
        int ar = rm + i*16 + (lane&15);
        int ap = (kk*4 + (lane>>4)) ^ (ar&7);
        af[i]  = *(const s16x8*)(As + ar*64 + ap*8);
        int br = cn + i*16 + (lane&15);
        int bp = (kk*4 + (lane>>4)) ^ (br&7);
        bfr[i] = *(const s16x8*)(Bs + br*64 + bp*8);
      }
      #pragma unroll
      for(int i=0;i<4;i++)
        #pragma unroll
        for(int j=0;j<4;j++)
          acc[i][j] = __builtin_amdgcn_mfma_f32_16x16x32_bf16(af[i], bfr[j], acc[i][j], 0,0,0);
    }
    __syncthreads();
  }
  #pragma unroll
  for(int i=0;i<4;i++){
    #pragma unroll
    for(int j=0;j<4;j++){
      int n  = n0 + cn + j*16 + (lane&15);
      int mB = m0 + rm + i*16 + ((lane>>4)<<2);
      #pragma unroll
      for(int r=0;r<4;r++){
        float val = acc[i][j][r];
        int m = mB + r;
        if (MODE==0){
          C0[(size_t)m*ldC + n] = f2b(val);
        } else {
          if (n < 256){
            float v2 = val + b2f(bias[n]);
            float sp = (v2 > 15.f) ? v2 : __logf(1.f + __expf(v2));
            C0[(size_t)m*256 + n] = f2b(sp);
          } else if (n < 272){
            C1[(size_t)m*16 + (n-256)] = f2b(val);
          }
        }
      }
    }
  }
}

// ---------------- depthwise conv + SiLU, 4 sequence positions per block ----------------
__global__ void k_conv(const u16* __restrict__ xz, const u16* __restrict__ cw,
                       const u16* __restrict__ cb, u16* __restrict__ xcf, u16* __restrict__ xcb_, int layer){
  int l0 = blockIdx.x*4, g = blockIdx.y, d = threadIdx.x;
  float w[4];
  #pragma unroll
  for(int j=0;j<4;j++) w[j] = b2f(cw[(size_t)layer*1024 + d*4 + j]);
  float bb = b2f(cb[layer*256 + d]);
  float xv[10];
  #pragma unroll
  for(int t=0;t<10;t++){
    int lp = l0 - 3 + t;
    xv[t] = (lp>=0 && lp<4096) ? b2f(xz[((size_t)g*4096 + lp)*512 + d]) : 0.f;
  }
  #pragma unroll
  for(int i=0;i<4;i++){
    float af = bb, ab = bb;
    #pragma unroll
    for(int j=0;j<4;j++){ af += w[j]*xv[i+j]; ab += w[j]*xv[i+6-j]; }
    af = af / (1.f + __expf(-af));
    ab = ab / (1.f + __expf(-ab));
    size_t o = ((size_t)g*4096 + (l0+i))*256 + d;
    xcf[o]  = f2b(af);
    xcb_[o] = f2b(ab);
  }
}

// ---------------- scan pass 1 ----------------
__global__ __launch_bounds__(256)
void k_scan1(const u16* __restrict__ df, const u16* __restrict__ db,
             const u16* __restrict__ uf, const u16* __restrict__ ub,
             const u16* __restrict__ bcf, const u16* __restrict__ bcb,
             const u16* __restrict__ Alog, const u16* __restrict__ Ablog,
             float* __restrict__ abuf, float* __restrict__ bbuf, int layer){
  int c = blockIdx.x, g = blockIdx.y, dir = blockIdx.z, d = threadIdx.x;
  const u16* dl = dir ? db : df;
  const u16* uu = dir ? ub : uf;
  const u16* bc = dir ? bcb : bcf;
  const u16* Al = dir ? Ablog : Alog;
  float An[8], h[8], ap[8];
  #pragma unroll
  for(int n=0;n<8;n++){
    An[n] = -__expf(b2f(Al[(size_t)layer*2048 + d*8 + n]));
    h[n] = 0.f; ap[n] = 1.f;
  }
  #pragma unroll 4
  for(int t=0;t<64;t++){
    int ts = c*64 + t;
    int tg = dir ? (4095 - ts) : ts;
    size_t rowo = (size_t)g*4096 + tg;
    float dv = b2f(dl[rowo*256 + d]);
    float uv = b2f(uu[rowo*256 + d]);
    uint4 bv = *(const uint4*)(bc + rowo*16);
    float bn[8]; unpack8(bv, bn);
    float du = dv*uv;
    #pragma unroll
    for(int n=0;n<8;n++){
      float da = __expf(dv*An[n]);
      h[n] = fmaf(da, h[n], du*bn[n]);
      ap[n] *= da;
    }
  }
  size_t base = ((((size_t)dir*8+g)*64 + c)*256 + d)*8;
  *(float4*)(abuf+base)   = (float4){ap[0],ap[1],ap[2],ap[3]};
  *(float4*)(abuf+base+4) = (float4){ap[4],ap[5],ap[6],ap[7]};
  *(float4*)(bbuf+base)   = (float4){h[0],h[1],h[2],h[3]};
  *(float4*)(bbuf+base+4) = (float4){h[4],h[5],h[6],h[7]};
}

// ---------------- scan pass 2 ----------------
__global__ void k_scan2(const float* __restrict__ abuf, const float* __restrict__ bbuf,
                        float* __restrict__ hs){
  int dblk = blockIdx.x, g = blockIdx.y, dir = blockIdx.z;
  int n = threadIdx.x & 7, dd = threadIdx.x >> 3;
  int d = dblk*32 + dd;
  float h = 0.f;
  size_t gofs = (((size_t)dir*8+g)*64);
  for(int c=0;c<64;c++){
    size_t idx = ((gofs + c)*256 + d)*8 + n;
    hs[idx] = h;
    h = fmaf(abuf[idx], h, bbuf[idx]);
  }
}

// ---------------- scan pass 3 ----------------
__global__ __launch_bounds__(256)
void k_scan3(const u16* __restrict__ df, const u16* __restrict__ db,
             const u16* __restrict__ uf, const u16* __restrict__ ub,
             const u16* __restrict__ bcf, const u16* __restrict__ bcb,
             const u16* __restrict__ Alog, const u16* __restrict__ Ablog,
             const u16* __restrict__ Dp, const u16* __restrict__ xz,
             const float* __restrict__ hs,
             u16* __restrict__ yf, u16* __restrict__ yb, int layer){
  int c = blockIdx.x, g = blockIdx.y, dir = blockIdx.z, d = threadIdx.x;
  const u16* dl = dir ? db : df;
  const u16* uu = dir ? ub : uf;
  const u16* bc = dir ? bcb : bcf;
  const u16* Al = dir ? Ablog : Alog;
  u16* yo = dir ? yb : yf;
  float An[8], h[8];
  size_t base = ((((size_t)dir*8+g)*64 + c)*256 + d)*8;
  float4 h0 = *(const float4*)(hs+base);
  float4 h1 = *(const float4*)(hs+base+4);
  h[0]=h0.x; h[1]=h0.y; h[2]=h0.z; h[3]=h0.w;
  h[4]=h1.x; h[5]=h1.y; h[6]=h1.z; h[7]=h1.w;
  #pragma unroll
  for(int n=0;n<8;n++) An[n] = -__expf(b2f(Al[(size_t)layer*2048 + d*8 + n]));
  float Dd = b2f(Dp[layer*256 + d]);
  #pragma unroll 2
  for(int t=0;t<64;t++){
    int ts = c*64 + t;
    int tg = dir ? (4095 - ts) : ts;
    size_t rowo = (size_t)g*4096 + tg;
    float dv = b2f(dl[rowo*256 + d]);
    float uv = b2f(uu[rowo*256 + d]);
    uint4 bv = *(const uint4*)(bc + rowo*16);
    uint4 cv = *(const uint4*)(bc + rowo*16 + 8);
    float bn[8], cn_[8];
    unpack8(bv, bn); unpack8(cv, cn_);
    float du = dv*uv;
    float y = 0.f;
    #pragma unroll
    for(int n=0;n<8;n++){
      float da = __expf(dv*An[n]);
      h[n] = fmaf(da, h[n], du*bn[n]);
      y = fmaf(h[n], cn_[n], y);
    }
    y += Dd*uv;
    float zv = b2f(xz[rowo*512 + 256 + d]);
    y *= zv / (1.f + __expf(-zv));
    yo[rowo*256 + d] = f2b(y);
  }
}

// ---------------- fused: out_proj GEMM (A = 0.5*(yf+yb)) + LN2 + residual + next-layer LN1 ----------------
// Tile 64(m) x 256(n, full), K=256, BK=64. 4 waves; wave w owns m-rows [w*16, w*16+16).
template<int LAST>
__global__ __launch_bounds__(256)
void k_outln(const u16* __restrict__ yf, const u16* __restrict__ yb,
             const u16* __restrict__ Bw,          // out_proj_w for this layer (256x256, row-major n x k)
             float* __restrict__ X, u16* __restrict__ xn_next,
             const u16* __restrict__ mnw, const u16* __restrict__ mnb,       // this layer
             const u16* __restrict__ lnw_n, const u16* __restrict__ lnb_n){  // next layer
  __shared__ u16 As[64*64];    // 8 KB
  __shared__ u16 Bs[256*64];   // 32 KB
  int tid = threadIdx.x, wid = tid>>6, lane = tid&63;
  int m0 = blockIdx.x*64;
  f32x4 acc[16];
  #pragma unroll
  for(int j=0;j<16;j++) acc[j] = (f32x4){0.f,0.f,0.f,0.f};
  int lrow = lane>>3;
  int scol = ((lane&7) ^ lrow) * 8;
  for(int k0=0;k0<256;k0+=64){
    // stage A = 0.5*(yf+yb), swizzled, via VALU + ds_write
    #pragma unroll
    for(int s=0;s<2;s++){
      int g2 = tid + s*256;            // 0..511
      int row = g2>>3, p = g2&7;
      size_t off = (size_t)(m0+row)*256 + k0 + p*8;
      uint4 a = *(const uint4*)(yf + off);
      uint4 b = *(const uint4*)(yb + off);
      float fa[8], fb[8]; unpack8(a,fa); unpack8(b,fb);
      u32 o[4];
      #pragma unroll
      for(int k2=0;k2<4;k2++){
        u16 lo = f2b(0.5f*(fa[2*k2]  +fb[2*k2]));
        u16 hi = f2b(0.5f*(fa[2*k2+1]+fb[2*k2+1]));
        o[k2] = (u32)lo | ((u32)hi<<16);
      }
      *(uint4*)(As + row*64 + ((p ^ (row&7))*8)) = (uint4){o[0],o[1],o[2],o[3]};
    }
    // stage B via global_load_lds (8 chunks of 8 rows per wave)
    #pragma unroll
    for(int it=0; it<8; ++it){
      int chunk = wid*8 + it;          // 0..31, rows chunk*8..+7
      int row = chunk*8 + lrow;
      gl_lds16(Bw + (size_t)row*256 + k0 + scol, Bs + chunk*512 + lane*8);
    }
    __syncthreads();
    #pragma unroll
    for(int kk=0;kk<2;kk++){
      int ar = wid*16 + (lane&15);
      int ap = (kk*4 + (lane>>4)) ^ (ar&7);
      s16x8 af = *(const s16x8*)(As + ar*64 + ap*8);
      #pragma unroll
      for(int j=0;j<16;j++){
        int br = j*16 + (lane&15);
        int bp = (kk*4 + (lane>>4)) ^ (br&7);
        s16x8 bf = *(const s16x8*)(Bs + br*64 + bp*8);
        acc[j] = __builtin_amdgcn_mfma_f32_16x16x32_bf16(af, bf, acc[j], 0,0,0);
      }
    }
    __syncthreads();
  }
  // ---- epilogue: LN over full row (256 cols distributed over 16 lanes x 16 frags) ----
  int quad = lane>>4;
  float sm[4]={0,0,0,0}, sq[4]={0,0,0,0};
  #pragma unroll
  for(int j=0;j<16;j++)
    #pragma unroll
    for(int r=0;r<4;r++){ float v=acc[j][r]; sm[r]+=v; sq[r]+=v*v; }
  #pragma unroll
  for(int o=1;o<16;o<<=1)
    #pragma unroll
    for(int r=0;r<4;r++){ sm[r]+=__shfl_xor(sm[r],o); sq[r]+=__shfl_xor(sq[r],o); }
  float mu[4], rs[4];
  #pragma unroll
  for(int r=0;r<4;r++){
    mu[r] = sm[r]*(1.f/256.f);
    float var = sq[r]*(1.f/256.f) - mu[r]*mu[r];
    rs[r] = rsqrtf(var + 1e-5f);
  }
  // LN2 + residual; overwrite acc with new residual values
  #pragma unroll
  for(int j=0;j<16;j++){
    int col = j*16 + (lane&15);
    float w = b2f(mnw[col]), bb = b2f(mnb[col]);
    #pragma unroll
    for(int r=0;r<4;r++){
      int m = m0 + wid*16 + quad*4 + r;
      float xn = X[(size_t)m*256 + col] + (acc[j][r]-mu[r])*rs[r]*w + bb;
      X[(size_t)m*256 + col] = xn;
      acc[j][r] = xn;
    }
  }
  if (!LAST){
    // next-layer LN1 on the updated residual, emit XN bf16
    float sm2[4]={0,0,0,0}, sq2[4]={0,0,0,0};
    #pragma unroll
    for(int j=0;j<16;j++)
      #pragma unroll
      for(int r=0;r<4;r++){ float v=acc[j][r]; sm2[r]+=v; sq2[r]+=v*v; }
    #pragma unroll
    for(int o=1;o<16;o<<=1)
      #pragma unroll
      for(int r=0;r<4;r++){ sm2[r]+=__shfl_xor(sm2[r],o); sq2[r]+=__shfl_xor(sq2[r],o); }
    float mu2[4], rs2[4];
    #pragma unroll
    for(int r=0;r<4;r++){
      mu2[r] = sm2[r]*(1.f/256.f);
      float var = sq2[r]*(1.f/256.f) - mu2[r]*mu2[r];
      rs2[r] = rsqrtf(var + 1e-5f);
    }
    #pragma unroll
    for(int j=0;j<16;j++){
      int col = j*16 + (lane&15);
      float w = b2f(lnw_n[col]), bb = b2f(lnb_n[col]);
      #pragma unroll
      for(int r=0;r<4;r++){
        int m = m0 + wid*16 + quad*4 + r;
        xn_next[(size_t)m*256 + col] = f2b((acc[j][r]-mu2[r])*rs2[r]*w + bb);
      }
    }
  }
}

// ---------------- final transpose ----------------
__global__ void k_tr(const float* __restrict__ x, void* __restrict__ out, const int* __restrict__ flag){
  __shared__ float tile[32][129];
  int isbf = *flag;
  int l0 = blockIdx.x*128, c0 = blockIdx.y*32, g = blockIdx.z;
  int tid = threadIdx.x;
  for(int it=0; it<16; ++it){
    int idx = it*256 + tid;
    int lj = idx>>5, ci = idx&31;
    tile[ci][lj] = x[((size_t)g*4096 + l0+lj)*256 + c0+ci];
  }
  __syncthreads();
  for(int it=0; it<16; ++it){
    int idx = it*256 + tid;
    int lj = idx&127, ci = idx>>7;
    size_t o = ((size_t)g*256 + c0+ci)*4096 + l0+lj;
    float v = tile[ci][lj];
    if (isbf) ((u16*)out)[o] = f2b(v);
    else      ((float*)out)[o] = v;
  }
}

extern "C" void kernel_launch(void* const* d_in, const int* in_sizes, int n_in,
                              void* d_out, int out_size, void* d_ws, size_t ws_size,
                              hipStream_t stream){
  (void)in_sizes; (void)n_in; (void)out_size; (void)ws_size;
  const int* rl = (const int*)d_in[15];

  char* ws = (char*)d_ws;
  float* X    = (float*)(ws);                    // 32 MB fp32 residual
  u16*  XN    = (u16*)(ws + 33554432);           // 16 MB
  u16*  XZ    = (u16*)(ws + 50331648);           // 32 MB (g,l,512)
  u16*  XCF   = (u16*)(ws + 83886080);           // 16 MB  (XCB contiguous after)
  u16*  XCB   = (u16*)(ws + 100663296);          // 16 MB
  u16*  DF    = (u16*)(ws + 117440512);          // 16 MB  (DB contiguous after)
  u16*  DB    = (u16*)(ws + 134217728);          // 16 MB
  u16*  BCF   = (u16*)(ws + 150994944);          // 1 MB   (BCB contiguous after)
  u16*  BCB   = (u16*)(ws + 152043520);          // 1 MB
  u16*  BCOMB = (u16*)(ws + 153092096);          // 0.75 MB
  float* ABUF = (float*)(ws + 153878528);        // 8 MB
  float* BBUF = (float*)(ws + 162267136);        // 8 MB
  u16*  YF    = (u16*)(ws + 153878528);          // 16 MB (reuses ABUF+BBUF after pass2)
  float* HS   = (float*)(ws + 170655744);        // 8 MB
  u16*  YB    = (u16*)(ws + 179044352);          // 16 MB
  u16*  WCVT  = (u16*)(ws + 195821568);          // ~1.7 MB canonical bf16 weights
  int*  FLAG  = (int*)(ws + 197918720);

  u16* W_lnw  = WCVT + 0;
  u16* W_lnb  = WCVT + 1024;
  u16* W_inp  = WCVT + 2048;
  u16* W_cw   = WCVT + 526336;
  u16* W_cb   = WCVT + 530432;
  u16* W_xp   = WCVT + 531456;
  u16* W_dtw  = WCVT + 564224;
  u16* W_dtb  = WCVT + 580608;
  u16* W_Al   = WCVT + 581632;
  u16* W_Abl  = WCVT + 589824;
  u16* W_D    = WCVT + 598016;
  u16* W_outp = WCVT + 599040;
  u16* W_mnw  = WCVT + 861184;
  u16* W_mnb  = WCVT + 862208;

  k_detect<<<1,64,0,stream>>>((const u16*)d_in[1], FLAG);

  CvtTable t;
  const int idxs[14] = {1,2,3,4,5,6,7,8,9,10,11,12,13,14};
  u16* dsts[14] = {W_lnw,W_lnb,W_inp,W_cw,W_cb,W_xp,W_dtw,W_dtb,W_Al,W_Abl,W_D,W_outp,W_mnw,W_mnb};
  const int ns[14] = {1024,1024,524288,4096,1024,32768,16384,1024,8192,8192,1024,262144,1024,1024};
  for(int i=0;i<14;i++){ t.src[i]=d_in[idxs[i]]; t.dst[i]=dsts[i]; t.n[i]=ns[i]; }
  k_cvt<<<dim3(32,14),256,0,stream>>>(t, FLAG);

  k_mean<<<dim3(32,8,8),256,0,stream>>>(d_in[0], rl, X, FLAG);
  k_prep<<<dim3(384,4),256,0,stream>>>(W_dtw, W_xp, BCOMB);
  k_ln1<<<8192,256,0,stream>>>(X, XN, W_lnw, W_lnb, 0);

  for(int layer=0; layer<4; ++layer){
    k_gemm<0><<<dim3(256,4),256,0,stream>>>(XN, W_inp + (size_t)layer*512*256, XZ, 512, nullptr, nullptr);
    k_conv<<<dim3(1024,8),256,0,stream>>>(XZ, W_cw, W_cb, XCF, XCB, layer);
    k_gemm<1><<<dim3(512,3),256,0,stream>>>(XCF, BCOMB + (size_t)layer*384*256, DF, 256, W_dtb + layer*256, BCF);
    k_scan1<<<dim3(64,8,2),256,0,stream>>>(DF,DB,XCF,XCB,BCF,BCB,W_Al,W_Abl,ABUF,BBUF,layer);
    k_scan2<<<dim3(8,8,2),256,0,stream>>>(ABUF,BBUF,HS);
    k_scan3<<<dim3(64,8,2),256,0,stream>>>(DF,DB,XCF,XCB,BCF,BCB,W_Al,W_Abl,W_D,XZ,HS,YF,YB,layer);
    if (layer < 3){
      k_outln<0><<<512,256,0,stream>>>(YF, YB, W_outp + (size_t)layer*256*256, X, XN,
                                       W_mnw + layer*256, W_mnb + layer*256,
                                       W_lnw + (layer+1)*256, W_lnb + (layer+1)*256);
    } else {
      k_outln<1><<<512,256,0,stream>>>(YF, YB, W_outp + (size_t)layer*256*256, X, XN,
                                       W_mnw + layer*256, W_mnb + layer*256,
                                       W_lnw, W_lnb);
    }
  }
  k_tr<<<dim3(32,8,8),256,0,stream>>>(X, d_out, FLAG);
}

// Round 5
// 1134.736 us; speedup vs baseline: 1.4559x; 1.0111x over previous
//
#include <hip/hip_runtime.h>
#include <hip/hip_bf16.h>
#include <cstdint>
#include <cstddef>

typedef unsigned short u16;
typedef unsigned int   u32;

typedef short s16x8 __attribute__((ext_vector_type(8)));
typedef float f32x4 __attribute__((ext_vector_type(4)));

__device__ __forceinline__ float b2f(u16 u){ u32 x = ((u32)u)<<16; float f; __builtin_memcpy(&f,&x,4); return f; }
__device__ __forceinline__ u16  f2b(float f){ u32 x; __builtin_memcpy(&x,&f,4); u32 r = x + 0x7FFFu + ((x>>16)&1u); return (u16)(r>>16); }

__device__ __forceinline__ void unpack8(uint4 v, float* o){
  o[0]=b2f((u16)v.x); o[1]=b2f((u16)(v.x>>16));
  o[2]=b2f((u16)v.y); o[3]=b2f((u16)(v.y>>16));
  o[4]=b2f((u16)v.z); o[5]=b2f((u16)(v.z>>16));
  o[6]=b2f((u16)v.w); o[7]=b2f((u16)(v.w>>16));
}

__device__ __forceinline__ void gl_lds16(const u16* g, u16* l){
  __builtin_amdgcn_global_load_lds((const __attribute__((address_space(1))) u32*)g,
                                   (__attribute__((address_space(3))) u32*)l, 16, 0, 0);
}

// ---------------- dtype detect ----------------
__global__ void k_detect(const u16* __restrict__ lnw, int* __restrict__ flag){
  if (threadIdx.x==0 && blockIdx.x==0) *flag = (lnw[0] == 0x3F80) ? 1 : 0;
}

// ---------------- convert weights to canonical bf16 ----------------
struct CvtTable { const void* src[14]; u16* dst[14]; int n[14]; };
__global__ void k_cvt(CvtTable t, const int* __restrict__ flag){
  int ti = blockIdx.y;
  int n = t.n[ti];
  int isbf = *flag;
  const u16*  sb = (const u16*)t.src[ti];
  const float* sf = (const float*)t.src[ti];
  u16* d = t.dst[ti];
  for (int i = blockIdx.x*256 + threadIdx.x; i < n; i += gridDim.x*256)
    d[i] = isbf ? sb[i] : f2b(sf[i]);
}

// ---------------- segment mean ----------------
__global__ void k_mean(const void* __restrict__ data, const int* __restrict__ rl,
                       float* __restrict__ x, const int* __restrict__ flag){
  __shared__ float tile[32][129];
  int isbf = *flag;
  const u16*  db = (const u16*)data;
  const float* df_ = (const float*)data;
  int g = blockIdx.z, c0 = blockIdx.y*32, l0 = blockIdx.x*128;
  int tid = threadIdx.x;
  int off=0; for(int i=0;i<g;i++) off += rl[i];
  int cnt = rl[g];
  float inv = 1.0f/(float)cnt;
  for(int it=0; it<16; ++it){
    int idx = it*256 + tid;
    int ci = idx>>7, lj = idx&127;
    float acc = 0.f;
    for(int b=0;b<cnt;b++){
      size_t gi = ((size_t)(off+b)*256 + (c0+ci)) * 4096 + (l0+lj);
      acc += isbf ? b2f(db[gi]) : df_[gi];
    }
    tile[ci][lj] = acc*inv;
  }
  __syncthreads();
  for(int it=0; it<16; ++it){
    int idx = it*256 + tid;
    int lj = idx>>5, ci = idx&31;
    x[ ((size_t)g*4096 + (l0+lj))*256 + (c0+ci) ] = tile[ci][lj];
  }
}

// ---------------- Bcomb prep ----------------
__global__ void k_prep(const u16* __restrict__ dtp, const u16* __restrict__ xpw, u16* __restrict__ bcomb){
  int layer = blockIdx.y, row = blockIdx.x, c = threadIdx.x;
  u16 out;
  if (row < 256){
    float acc = 0.f;
    #pragma unroll
    for(int r=0;r<16;r++)
      acc += b2f(dtp[(size_t)layer*4096 + row*16 + r]) * b2f(xpw[(size_t)layer*8192 + r*256 + c]);
    out = f2b(acc);
  } else if (row < 272){
    out = xpw[(size_t)layer*8192 + (16 + row - 256)*256 + c];
  } else {
    out = 0;
  }
  bcomb[((size_t)layer*384 + row)*256 + c] = out;
}

// ---------------- LN1 (layer 0 only) ----------------
__global__ void k_ln1(const float* __restrict__ x, u16* __restrict__ xn,
                      const u16* __restrict__ w, const u16* __restrict__ b, int layer){
  int wid = threadIdx.x>>6, lane = threadIdx.x&63;
  int row = blockIdx.x*4 + wid;
  const float* xr = x + (size_t)row*256;
  float4 v = *(const float4*)(xr + lane*4);
  float s = v.x+v.y+v.z+v.w;
  float q = v.x*v.x+v.y*v.y+v.z*v.z+v.w*v.w;
  for(int o=32;o;o>>=1){ s += __shfl_xor(s,o); q += __shfl_xor(q,o); }
  float mu = s*(1.f/256.f);
  float var = q*(1.f/256.f) - mu*mu;
  float rs = rsqrtf(var + 1e-5f);
  const u16* wp = w + layer*256 + lane*4;
  const u16* bp = b + layer*256 + lane*4;
  float vv[4] = {v.x,v.y,v.z,v.w};
  u16 o4[4];
  #pragma unroll
  for(int k2=0;k2<4;k2++) o4[k2] = f2b( (vv[k2]-mu)*rs*b2f(wp[k2]) + b2f(bp[k2]) );
  uint2 ov; ov.x = (u32)o4[0] | ((u32)o4[1]<<16); ov.y = (u32)o4[2] | ((u32)o4[3]<<16);
  *(uint2*)(xn + (size_t)row*256 + lane*4) = ov;
}

// ---------------- bf16 NT GEMM, 128x128 tile, BK=64, K=256, XOR-swizzled LDS ----------------
template<int MODE>
__global__ __launch_bounds__(256)
void k_gemm(const u16* __restrict__ A, const u16* __restrict__ B,
            u16* __restrict__ C0, int ldC,
            const u16* __restrict__ bias, u16* __restrict__ C1){
  __shared__ u16 As[128*64];
  __shared__ u16 Bs[128*64];
  int tid = threadIdx.x, wid = tid>>6, lane = tid&63;
  int m0 = blockIdx.x*128, n0 = blockIdx.y*128;
  f32x4 acc[4][4];
  #pragma unroll
  for(int i=0;i<4;i++)
    #pragma unroll
    for(int j=0;j<4;j++) acc[i][j] = (f32x4){0.f,0.f,0.f,0.f};
  int lrow  = lane>>3;
  int scol  = ((lane&7) ^ lrow) * 8;
  int rm = (wid&1)*64, cn = (wid>>1)*64;
  for(int k0=0;k0<256;k0+=64){
    #pragma unroll
    for(int it=0; it<4; ++it){
      int chunk = wid*4 + it;
      int row = chunk*8 + lrow;
      gl_lds16(A + (size_t)(m0+row)*256 + k0 + scol, As + chunk*512 + lane*8);
      gl_lds16(B + (size_t)(n0+row)*256 + k0 + scol, Bs + chunk*512 + lane*8);
    }
    __syncthreads();
    #pragma unroll
    for(int kk=0;kk<2;kk++){
      s16x8 af[4], bfr[4];
      #pragma unroll
      for(int i=0;i<4;i++){
        int ar = rm + i*16 + (lane&15);
        int ap = (kk*4 + (lane>>4)) ^ (ar&7);
        af[i]  = *(const s16x8*)(As + ar*64 + ap*8);
        int br = cn + i*16 + (lane&15);
        int bp = (kk*4 + (lane>>4)) ^ (br&7);
        bfr[i] = *(const s16x8*)(Bs + br*64 + bp*8);
      }
      #pragma unroll
      for(int i=0;i<4;i++)
        #pragma unroll
        for(int j=0;j<4;j++)
          acc[i][j] = __builtin_amdgcn_mfma_f32_16x16x32_bf16(af[i], bfr[j], acc[i][j], 0,0,0);
    }
    __syncthreads();
  }
  #pragma unroll
  for(int i=0;i<4;i++){
    #pragma unroll
    for(int j=0;j<4;j++){
      int n  = n0 + cn + j*16 + (lane&15);
      int mB = m0 + rm + i*16 + ((lane>>4)<<2);
      #pragma unroll
      for(int r=0;r<4;r++){
        float val = acc[i][j][r];
        int m = mB + r;
        if (MODE==0){
          C0[(size_t)m*ldC + n] = f2b(val);
        } else {
          if (n < 256){
            float v2 = val + b2f(bias[n]);
            float sp = (v2 > 15.f) ? v2 : __logf(1.f + __expf(v2));
            C0[(size_t)m*256 + n] = f2b(sp);
          } else if (n < 272){
            C1[(size_t)m*16 + (n-256)] = f2b(val);
          }
        }
      }
    }
  }
}

// ---------------- depthwise conv + SiLU, 4 sequence positions per block ----------------
__global__ void k_conv(const u16* __restrict__ xz, const u16* __restrict__ cw,
                       const u16* __restrict__ cb, u16* __restrict__ xcf, u16* __restrict__ xcb_, int layer){
  int l0 = blockIdx.x*4, g = blockIdx.y, d = threadIdx.x;
  float w[4];
  #pragma unroll
  for(int j=0;j<4;j++) w[j] = b2f(cw[(size_t)layer*1024 + d*4 + j]);
  float bb = b2f(cb[layer*256 + d]);
  float xv[10];
  #pragma unroll
  for(int t=0;t<10;t++){
    int lp = l0 - 3 + t;
    xv[t] = (lp>=0 && lp<4096) ? b2f(xz[((size_t)g*4096 + lp)*512 + d]) : 0.f;
  }
  #pragma unroll
  for(int i=0;i<4;i++){
    float af = bb, ab = bb;
    #pragma unroll
    for(int j=0;j<4;j++){ af += w[j]*xv[i+j]; ab += w[j]*xv[i+6-j]; }
    af = af / (1.f + __expf(-af));
    ab = ab / (1.f + __expf(-ab));
    size_t o = ((size_t)g*4096 + (l0+i))*256 + d;
    xcf[o]  = f2b(af);
    xcb_[o] = f2b(ab);
  }
}

// ---------------- scan pass 1 ----------------
__global__ __launch_bounds__(256)
void k_scan1(const u16* __restrict__ df, const u16* __restrict__ db,
             const u16* __restrict__ uf, const u16* __restrict__ ub,
             const u16* __restrict__ bcf, const u16* __restrict__ bcb,
             const u16* __restrict__ Alog, const u16* __restrict__ Ablog,
             float* __restrict__ abuf, float* __restrict__ bbuf, int layer){
  int c = blockIdx.x, g = blockIdx.y, dir = blockIdx.z, d = threadIdx.x;
  const u16* dl = dir ? db : df;
  const u16* uu = dir ? ub : uf;
  const u16* bc = dir ? bcb : bcf;
  const u16* Al = dir ? Ablog : Alog;
  float An[8], h[8], ap[8];
  #pragma unroll
  for(int n=0;n<8;n++){
    An[n] = -__expf(b2f(Al[(size_t)layer*2048 + d*8 + n]));
    h[n] = 0.f; ap[n] = 1.f;
  }
  #pragma unroll 4
  for(int t=0;t<64;t++){
    int ts = c*64 + t;
    int tg = dir ? (4095 - ts) : ts;
    size_t rowo = (size_t)g*4096 + tg;
    float dv = b2f(dl[rowo*256 + d]);
    float uv = b2f(uu[rowo*256 + d]);
    uint4 bv = *(const uint4*)(bc + rowo*16);
    float bn[8]; unpack8(bv, bn);
    float du = dv*uv;
    #pragma unroll
    for(int n=0;n<8;n++){
      float da = __expf(dv*An[n]);
      h[n] = fmaf(da, h[n], du*bn[n]);
      ap[n] *= da;
    }
  }
  size_t base = ((((size_t)dir*8+g)*64 + c)*256 + d)*8;
  *(float4*)(abuf+base)   = (float4){ap[0],ap[1],ap[2],ap[3]};
  *(float4*)(abuf+base+4) = (float4){ap[4],ap[5],ap[6],ap[7]};
  *(float4*)(bbuf+base)   = (float4){h[0],h[1],h[2],h[3]};
  *(float4*)(bbuf+base+4) = (float4){h[4],h[5],h[6],h[7]};
}

// ---------------- scan pass 2 ----------------
__global__ void k_scan2(const float* __restrict__ abuf, const float* __restrict__ bbuf,
                        float* __restrict__ hs){
  int dblk = blockIdx.x, g = blockIdx.y, dir = blockIdx.z;
  int n = threadIdx.x & 7, dd = threadIdx.x >> 3;
  int d = dblk*32 + dd;
  float h = 0.f;
  size_t gofs = (((size_t)dir*8+g)*64);
  for(int c=0;c<64;c++){
    size_t idx = ((gofs + c)*256 + d)*8 + n;
    hs[idx] = h;
    h = fmaf(abuf[idx], h, bbuf[idx]);
  }
}

// ---------------- fused: scan pass 3 (both dirs) + 0.5*(yf+yb)*silu(z) + out_proj GEMM + LN2 + residual + next LN1 ----------------
// Block = (chunk c, group g). Phase A: replay bwd chunk (descending rows) then fwd chunk into padded LDS A-tile.
// Phase B: 64x256 * 256x256 MFMA GEMM + LN epilogue.
#define AP 264   // padded A-tile row stride in u16 (264*2=528B, 16B-aligned)
template<int LAST>
__global__ __launch_bounds__(256)
void k_scanout(const u16* __restrict__ df, const u16* __restrict__ db,
               const u16* __restrict__ uf, const u16* __restrict__ ub,
               const u16* __restrict__ bcf, const u16* __restrict__ bcb,
               const u16* __restrict__ Alog, const u16* __restrict__ Ablog,
               const u16* __restrict__ Dp, const u16* __restrict__ xz,
               const float* __restrict__ hs,
               const u16* __restrict__ Bw,
               float* __restrict__ X, u16* __restrict__ xn_next,
               const u16* __restrict__ mnw, const u16* __restrict__ mnb,
               const u16* __restrict__ lnw_n, const u16* __restrict__ lnb_n,
               int layer){
  __shared__ u16 As[64*AP];    // ~33 KB
  __shared__ u16 Bs[256*64];   // 32 KB
  int tid = threadIdx.x;
  int c = blockIdx.x, g = blockIdx.y;
  int l0 = c*64;
  int d = tid;
  float Dd = b2f(Dp[layer*256 + d]);
  float An[8], h[8];
  // ---- bwd chunk (global chunk index 63-c), rows descending ----
  {
    #pragma unroll
    for(int n=0;n<8;n++) An[n] = -__expf(b2f(Ablog[(size_t)layer*2048 + d*8 + n]));
    size_t base = ((((size_t)8+g)*64 + (63-c))*256 + d)*8;
    float4 h0 = *(const float4*)(hs+base);
    float4 h1 = *(const float4*)(hs+base+4);
    h[0]=h0.x; h[1]=h0.y; h[2]=h0.z; h[3]=h0.w;
    h[4]=h1.x; h[5]=h1.y; h[6]=h1.z; h[7]=h1.w;
    #pragma unroll 2
    for(int q=0;q<64;q++){
      int t = 63 - q;
      size_t rowo = (size_t)g*4096 + l0 + t;
      float dv = b2f(db[rowo*256 + d]);
      float uv = b2f(ub[rowo*256 + d]);
      uint4 bv = *(const uint4*)(bcb + rowo*16);
      uint4 cv = *(const uint4*)(bcb + rowo*16 + 8);
      float bn[8], cn_[8];
      unpack8(bv, bn); unpack8(cv, cn_);
      float du = dv*uv;
      float y = 0.f;
      #pragma unroll
      for(int n=0;n<8;n++){
        float da = __expf(dv*An[n]);
        h[n] = fmaf(da, h[n], du*bn[n]);
        y = fmaf(h[n], cn_[n], y);
      }
      y += Dd*uv;
      float zv = b2f(xz[rowo*512 + 256 + d]);
      y *= 0.5f * zv / (1.f + __expf(-zv));
      As[t*AP + d] = f2b(y);
    }
  }
  // ---- fwd chunk c, rows ascending; accumulate ----
  {
    #pragma unroll
    for(int n=0;n<8;n++) An[n] = -__expf(b2f(Alog[(size_t)layer*2048 + d*8 + n]));
    size_t base = (((size_t)g*64 + c)*256 + d)*8;
    float4 h0 = *(const float4*)(hs+base);
    float4 h1 = *(const float4*)(hs+base+4);
    h[0]=h0.x; h[1]=h0.y; h[2]=h0.z; h[3]=h0.w;
    h[4]=h1.x; h[5]=h1.y; h[6]=h1.z; h[7]=h1.w;
    #pragma unroll 2
    for(int t=0;t<64;t++){
      size_t rowo = (size_t)g*4096 + l0 + t;
      float dv = b2f(df[rowo*256 + d]);
      float uv = b2f(uf[rowo*256 + d]);
      uint4 bv = *(const uint4*)(bcf + rowo*16);
      uint4 cv = *(const uint4*)(bcf + rowo*16 + 8);
      float bn[8], cn_[8];
      unpack8(bv, bn); unpack8(cv, cn_);
      float du = dv*uv;
      float y = 0.f;
      #pragma unroll
      for(int n=0;n<8;n++){
        float da = __expf(dv*An[n]);
        h[n] = fmaf(da, h[n], du*bn[n]);
        y = fmaf(h[n], cn_[n], y);
      }
      y += Dd*uv;
      float zv = b2f(xz[rowo*512 + 256 + d]);
      y *= 0.5f * zv / (1.f + __expf(-zv));
      int off = t*AP + d;
      As[off] = f2b(b2f(As[off]) + y);
    }
  }
  // ---- phase B: GEMM A(64x256) * B^T(256x256) ----
  int wid = tid>>6, lane = tid&63;
  f32x4 acc[16];
  #pragma unroll
  for(int j=0;j<16;j++) acc[j] = (f32x4){0.f,0.f,0.f,0.f};
  int lrow = lane>>3;
  int scol = ((lane&7) ^ lrow) * 8;
  for(int k0=0;k0<256;k0+=64){
    #pragma unroll
    for(int it=0; it<8; ++it){
      int chunk = wid*8 + it;
      int row = chunk*8 + lrow;
      gl_lds16(Bw + (size_t)row*256 + k0 + scol, Bs + chunk*512 + lane*8);
    }
    __syncthreads();
    #pragma unroll
    for(int kk=0;kk<2;kk++){
      int ar = wid*16 + (lane&15);
      s16x8 af = *(const s16x8*)(As + ar*AP + k0 + kk*32 + (lane>>4)*8);
      #pragma unroll
      for(int j=0;j<16;j++){
        int br = j*16 + (lane&15);
        int bp = (kk*4 + (lane>>4)) ^ (br&7);
        s16x8 bf = *(const s16x8*)(Bs + br*64 + bp*8);
        acc[j] = __builtin_amdgcn_mfma_f32_16x16x32_bf16(af, bf, acc[j], 0,0,0);
      }
    }
    __syncthreads();
  }
  // ---- epilogue: LN2 + residual (+ next-layer LN1) ----
  size_t gm0 = (size_t)g*4096 + l0;
  int quad = lane>>4;
  float sm[4]={0,0,0,0}, sq[4]={0,0,0,0};
  #pragma unroll
  for(int j=0;j<16;j++)
    #pragma unroll
    for(int r=0;r<4;r++){ float v=acc[j][r]; sm[r]+=v; sq[r]+=v*v; }
  #pragma unroll
  for(int o=1;o<16;o<<=1)
    #pragma unroll
    for(int r=0;r<4;r++){ sm[r]+=__shfl_xor(sm[r],o); sq[r]+=__shfl_xor(sq[r],o); }
  float mu[4], rs[4];
  #pragma unroll
  for(int r=0;r<4;r++){
    mu[r] = sm[r]*(1.f/256.f);
    float var = sq[r]*(1.f/256.f) - mu[r]*mu[r];
    rs[r] = rsqrtf(var + 1e-5f);
  }
  #pragma unroll
  for(int j=0;j<16;j++){
    int col = j*16 + (lane&15);
    float w = b2f(mnw[col]), bb = b2f(mnb[col]);
    #pragma unroll
    for(int r=0;r<4;r++){
      size_t m = gm0 + wid*16 + quad*4 + r;
      float xn = X[m*256 + col] + (acc[j][r]-mu[r])*rs[r]*w + bb;
      X[m*256 + col] = xn;
      acc[j][r] = xn;
    }
  }
  if (!LAST){
    float sm2[4]={0,0,0,0}, sq2[4]={0,0,0,0};
    #pragma unroll
    for(int j=0;j<16;j++)
      #pragma unroll
      for(int r=0;r<4;r++){ float v=acc[j][r]; sm2[r]+=v; sq2[r]+=v*v; }
    #pragma unroll
    for(int o=1;o<16;o<<=1)
      #pragma unroll
      for(int r=0;r<4;r++){ sm2[r]+=__shfl_xor(sm2[r],o); sq2[r]+=__shfl_xor(sq2[r],o); }
    float mu2[4], rs2[4];
    #pragma unroll
    for(int r=0;r<4;r++){
      mu2[r] = sm2[r]*(1.f/256.f);
      float var = sq2[r]*(1.f/256.f) - mu2[r]*mu2[r];
      rs2[r] = rsqrtf(var + 1e-5f);
    }
    #pragma unroll
    for(int j=0;j<16;j++){
      int col = j*16 + (lane&15);
      float w = b2f(lnw_n[col]), bb = b2f(lnb_n[col]);
      #pragma unroll
      for(int r=0;r<4;r++){
        size_t m = gm0 + wid*16 + quad*4 + r;
        xn_next[m*256 + col] = f2b((acc[j][r]-mu2[r])*rs2[r]*w + bb);
      }
    }
  }
}

// ---------------- final transpose ----------------
__global__ void k_tr(const float* __restrict__ x, void* __restrict__ out, const int* __restrict__ flag){
  __shared__ float tile[32][129];
  int isbf = *flag;
  int l0 = blockIdx.x*128, c0 = blockIdx.y*32, g = blockIdx.z;
  int tid = threadIdx.x;
  for(int it=0; it<16; ++it){
    int idx = it*256 + tid;
    int lj = idx>>5, ci = idx&31;
    tile[ci][lj] = x[((size_t)g*4096 + l0+lj)*256 + c0+ci];
  }
  __syncthreads();
  for(int it=0; it<16; ++it){
    int idx = it*256 + tid;
    int lj = idx&127, ci = idx>>7;
    size_t o = ((size_t)g*256 + c0+ci)*4096 + l0+lj;
    float v = tile[ci][lj];
    if (isbf) ((u16*)out)[o] = f2b(v);
    else      ((float*)out)[o] = v;
  }
}

extern "C" void kernel_launch(void* const* d_in, const int* in_sizes, int n_in,
                              void* d_out, int out_size, void* d_ws, size_t ws_size,
                              hipStream_t stream){
  (void)in_sizes; (void)n_in; (void)out_size; (void)ws_size;
  const int* rl = (const int*)d_in[15];

  char* ws = (char*)d_ws;
  float* X    = (float*)(ws);                    // 32 MB fp32 residual
  u16*  XN    = (u16*)(ws + 33554432);           // 16 MB
  u16*  XZ    = (u16*)(ws + 50331648);           // 32 MB (g,l,512)
  u16*  XCF   = (u16*)(ws + 83886080);           // 16 MB  (XCB contiguous after)
  u16*  XCB   = (u16*)(ws + 100663296);          // 16 MB
  u16*  DF    = (u16*)(ws + 117440512);          // 16 MB  (DB contiguous after)
  u16*  DB    = (u16*)(ws + 134217728);          // 16 MB
  u16*  BCF   = (u16*)(ws + 150994944);          // 1 MB   (BCB contiguous after)
  u16*  BCB   = (u16*)(ws + 152043520);          // 1 MB
  u16*  BCOMB = (u16*)(ws + 153092096);          // 0.75 MB
  float* ABUF = (float*)(ws + 153878528);        // 8 MB
  float* BBUF = (float*)(ws + 162267136);        // 8 MB
  float* HS   = (float*)(ws + 170655744);        // 8 MB
  u16*  WCVT  = (u16*)(ws + 195821568);          // ~1.7 MB canonical bf16 weights
  int*  FLAG  = (int*)(ws + 197918720);

  u16* W_lnw  = WCVT + 0;
  u16* W_lnb  = WCVT + 1024;
  u16* W_inp  = WCVT + 2048;
  u16* W_cw   = WCVT + 526336;
  u16* W_cb   = WCVT + 530432;
  u16* W_xp   = WCVT + 531456;
  u16* W_dtw  = WCVT + 564224;
  u16* W_dtb  = WCVT + 580608;
  u16* W_Al   = WCVT + 581632;
  u16* W_Abl  = WCVT + 589824;
  u16* W_D    = WCVT + 598016;
  u16* W_outp = WCVT + 599040;
  u16* W_mnw  = WCVT + 861184;
  u16* W_mnb  = WCVT + 862208;

  k_detect<<<1,64,0,stream>>>((const u16*)d_in[1], FLAG);

  CvtTable t;
  const int idxs[14] = {1,2,3,4,5,6,7,8,9,10,11,12,13,14};
  u16* dsts[14] = {W_lnw,W_lnb,W_inp,W_cw,W_cb,W_xp,W_dtw,W_dtb,W_Al,W_Abl,W_D,W_outp,W_mnw,W_mnb};
  const int ns[14] = {1024,1024,524288,4096,1024,32768,16384,1024,8192,8192,1024,262144,1024,1024};
  for(int i=0;i<14;i++){ t.src[i]=d_in[idxs[i]]; t.dst[i]=dsts[i]; t.n[i]=ns[i]; }
  k_cvt<<<dim3(32,14),256,0,stream>>>(t, FLAG);

  k_mean<<<dim3(32,8,8),256,0,stream>>>(d_in[0], rl, X, FLAG);
  k_prep<<<dim3(384,4),256,0,stream>>>(W_dtw, W_xp, BCOMB);
  k_ln1<<<8192,256,0,stream>>>(X, XN, W_lnw, W_lnb, 0);

  for(int layer=0; layer<4; ++layer){
    k_gemm<0><<<dim3(256,4),256,0,stream>>>(XN, W_inp + (size_t)layer*512*256, XZ, 512, nullptr, nullptr);
    k_conv<<<dim3(1024,8),256,0,stream>>>(XZ, W_cw, W_cb, XCF, XCB, layer);
    k_gemm<1><<<dim3(512,3),256,0,stream>>>(XCF, BCOMB + (size_t)layer*384*256, DF, 256, W_dtb + layer*256, BCF);
    k_scan1<<<dim3(64,8,2),256,0,stream>>>(DF,DB,XCF,XCB,BCF,BCB,W_Al,W_Abl,ABUF,BBUF,layer);
    k_scan2<<<dim3(8,8,2),256,0,stream>>>(ABUF,BBUF,HS);
    if (layer < 3){
      k_scanout<0><<<dim3(64,8),256,0,stream>>>(DF,DB,XCF,XCB,BCF,BCB,W_Al,W_Abl,W_D,XZ,HS,
                                                W_outp + (size_t)layer*256*256, X, XN,
                                                W_mnw + layer*256, W_mnb + layer*256,
                                                W_lnw + (layer+1)*256, W_lnb + (layer+1)*256, layer);
    } else {
      k_scanout<1><<<dim3(64,8),256,0,stream>>>(DF,DB,XCF,XCB,BCF,BCB,W_Al,W_Abl,W_D,XZ,HS,
                                                W_outp + (size_t)layer*256*256, X, XN,
                                                W_mnw + layer*256, W_mnb + layer*256,
                                                W_lnw, W_lnb, layer);
    }
  }
  k_tr<<<dim3(32,8,8),256,0,stream>>>(X, d_out, FLAG);
}